// Round 15
// baseline (320.414 us; speedup 1.0000x reference)
//
#include <hip/hip_runtime.h>
#include <hip/hip_fp16.h>

// ---------------------------------------------------------------------------
// CrowdGNN: 2-layer GCN, N=500k nodes, E=8M edges (+ implicit self loops).
// Round-14 = round-10 structure + PHANTOM-EDGE FIX in k_sort:
//   Round-10 bug: unconditional 8-wide atomics processed ceil(c/4096)*4096
//   slots; for c>8192 that is 12288 > cap=10240 -> phantom v=0 entries
//   inflated node-0 counts, shifted all rowStarts, and pass-2 scatter
//   overflowed into the NEXT bin's slotsB (absmax 19.7). Counting sort is
//   NOT phantom-tolerant (round-9 accumulators were). Fix: predicate both
//   passes with (j+q < c).
// Structure: partition (bin by dst>>9, LDS-staged coalesced writes)
//   -> k_sort (per-bin counting sort by dst + fused deg/dinv/y, ONE packed
//      LDS atomic/edge) -> thread-per-node layer1/layer2 with REGISTER int
//      accumulation (zero LDS atomics, deterministic).
// Fixed-point: wq q11 in slot; y q11 s4; acc1 q22; acc2 q20.
// ---------------------------------------------------------------------------

typedef unsigned long long u64;
typedef long long ll2 __attribute__((ext_vector_type(2)));
typedef short s4 __attribute__((ext_vector_type(4)));

#define NPB_SHIFT 9
#define NPB 512
#define MAX_BINS 1024
#define PART_THREADS 1024
#define PART_EPT 4
#define PART_CHUNK (PART_THREADS * PART_EPT)   // 4096 edges per block
#define SORT_THREADS 512

#define Q11        2048.0f
#define INV11      (1.0f / 2048.0f)
#define A1_INV     (1.0f / 4194304.0f)   // q22 = q11*q11
#define A2_INV     (1.0f / 1048576.0f)   // q20 = q11 * 2^9

// Detect int64 vs int32 edge_index: int64 values < 2^31 => odd words all zero.
__global__ __launch_bounds__(1024)
void k_detect(const unsigned int* __restrict__ idx_words, int nCheck, int* flag) {
    __shared__ int cnt;
    if (threadIdx.x == 0) cnt = 0;
    __syncthreads();
    int local = 0;
    for (int i = threadIdx.x; i < nCheck; i += blockDim.x)
        local += (idx_words[2 * i + 1] != 0u) ? 1 : 0;
    if (local) atomicAdd(&cnt, local);
    __syncthreads();
    if (threadIdx.x == 0) *flag = (cnt < 8) ? 1 : 0;
}

__global__ __launch_bounds__(256)
void k_zero(int* __restrict__ p, int n) {
    int i = blockIdx.x * blockDim.x + threadIdx.x;
    if (i < n) p[i] = 0;
}

// Bin-sorted-staging partition (unchanged from round 8/9).
__global__ __launch_bounds__(PART_THREADS)
void k_partition(const void* __restrict__ idx, const float* __restrict__ ew,
                 int* __restrict__ gCnt, u64* __restrict__ slots,
                 int E, int B, int cap, const int* __restrict__ flag) {
    __shared__ int lcnt[MAX_BINS];
    __shared__ int lbase[MAX_BINS];
    __shared__ int lstart[MAX_BINS];
    __shared__ u64 sPay[PART_CHUNK];
    __shared__ unsigned sAddr[PART_CHUNK];
    __shared__ int waveSum[PART_THREADS / 64];

    const bool is64 = (*flag != 0);
    const int tid = threadIdx.x;
    for (int i = tid; i < MAX_BINS; i += PART_THREADS) lcnt[i] = 0;
    __syncthreads();

    const int base_e = blockIdx.x * PART_CHUNK;
    const int nValid = min(PART_CHUNK, E - base_e);

    u64 pay[PART_EPT];
    int bin_[PART_EPT], r_[PART_EPT];
#pragma unroll
    for (int i = 0; i < PART_EPT; ++i) {
        int e = base_e + i * PART_THREADS + tid;
        bin_[i] = -1;
        if (e < E) {
            int s, d;
            if (is64) {
                const long long* p = (const long long*)idx;
                s = (int)__builtin_nontemporal_load(p + e);
                d = (int)__builtin_nontemporal_load(p + (long long)E + e);
            } else {
                const int* p = (const int*)idx;
                s = __builtin_nontemporal_load(p + e);
                d = __builtin_nontemporal_load(p + E + e);
            }
            float w = __builtin_nontemporal_load(ew + e);
            int bin = d >> NPB_SHIFT;
            unsigned wq = min((unsigned)__float2int_rn(w * Q11), 2047u);
            unsigned pk = ((unsigned)(d & (NPB - 1)) << 23) | (unsigned)s;
            pay[i] = ((u64)wq << 32) | pk;
            bin_[i] = bin;
            r_[i] = atomicAdd(&lcnt[bin], 1);
        }
    }
    __syncthreads();

    {
        const int lane = tid & 63, wid = tid >> 6;
        const int v = lcnt[tid];
        int inc = v;
#pragma unroll
        for (int off = 1; off < 64; off <<= 1) {
            int t = __shfl_up(inc, off, 64);
            if (lane >= off) inc += t;
        }
        if (lane == 63) waveSum[wid] = inc;
        __syncthreads();
        if (wid == 0) {
            const int NW = PART_THREADS / 64;
            int wv = (lane < NW) ? waveSum[lane] : 0;
            int winc = wv;
#pragma unroll
            for (int off = 1; off < NW; off <<= 1) {
                int t = __shfl_up(winc, off, 64);
                if (lane >= off) winc += t;
            }
            if (lane < NW) waveSum[lane] = winc - wv;
        }
        __syncthreads();
        lstart[tid] = inc - v + waveSum[wid];
        lbase[tid] = (v > 0 && tid < B) ? atomicAdd(&gCnt[tid], v) : 0;
    }
    __syncthreads();

#pragma unroll
    for (int i = 0; i < PART_EPT; ++i) {
        if (bin_[i] >= 0) {
            int si = lstart[bin_[i]] + r_[i];
            long long pos = (long long)lbase[bin_[i]] + r_[i];
            sPay[si] = pay[i];
            sAddr[si] = (pos < cap)
                      ? (unsigned)((long long)bin_[i] * cap + pos)
                      : 0xFFFFFFFFu;
        }
    }
    __syncthreads();

    for (int k = tid; k < nValid; k += PART_THREADS) {
        unsigned a = sAddr[k];
        if (a != 0xFFFFFFFFu) slots[a] = sPay[k];
    }
}

// 8-wide slot fetch; entries past c are zero-filled but MUST NOT be used by
// count-based consumers (predicate on j+q<c).
__device__ __forceinline__ void load8(const u64* __restrict__ sp, int j, int c,
                                      u64* __restrict__ v) {
    if (j + 7 < c) {
#pragma unroll
        for (int q = 0; q < 4; ++q) {
            ll2 t = *((const ll2*)(sp + j) + q);
            v[2 * q]     = (u64)t.x;
            v[2 * q + 1] = (u64)t.y;
        }
    } else {
#pragma unroll
        for (int q = 0; q < 8; ++q)
            v[q] = (j + q < c) ? sp[j + q] : 0ULL;
    }
}

// Per-bin counting sort + fused deg/dinv/y. Grid = B bins, 512 threads.
__global__ __launch_bounds__(SORT_THREADS)
void k_sort(const u64* __restrict__ slotsA, const int* __restrict__ gCnt,
            const float4* __restrict__ x, u64* __restrict__ slotsB,
            int* __restrict__ rowStart, int* __restrict__ rowCnt,
            float* __restrict__ dinv, s4* __restrict__ y, int N, int cap) {
    __shared__ unsigned degcnt[NPB];   // count<<20 | wq-sum
    __shared__ int posc[NPB];
    __shared__ int waveSum[SORT_THREADS / 64];
    const int b = blockIdx.x, tid = threadIdx.x;
    degcnt[tid] = 0u;
    __syncthreads();

    const int c = min(gCnt[b], cap);
    const u64* sp = slotsA + (size_t)b * cap;
    const int CH = SORT_THREADS * 8;

    // pass 1: one packed LDS atomic per VALID edge (predicated: no phantoms!)
    for (int base = 0; base < c; base += CH) {
        int j = base + (tid << 3);
        u64 v[8];
        load8(sp, j, c, v);
#pragma unroll
        for (int q = 0; q < 8; ++q) {
            if (j + q < c)
                atomicAdd(&degcnt[((unsigned)v[q]) >> 23],
                          (1u << 20) | (unsigned)(v[q] >> 32));
        }
    }
    __syncthreads();

    // exclusive scan of counts -> run starts
    const unsigned dc = degcnt[tid];
    const int cntN = (int)(dc >> 20);
    int stv;
    {
        const int lane = tid & 63, wid = tid >> 6;
        int inc = cntN;
#pragma unroll
        for (int off = 1; off < 64; off <<= 1) {
            int t = __shfl_up(inc, off, 64);
            if (lane >= off) inc += t;
        }
        if (lane == 63) waveSum[wid] = inc;
        __syncthreads();
        if (wid == 0) {
            const int NW = SORT_THREADS / 64;
            int wv = (lane < NW) ? waveSum[lane] : 0;
            int winc = wv;
#pragma unroll
            for (int off = 1; off < NW; off <<= 1) {
                int t = __shfl_up(winc, off, 64);
                if (lane >= off) winc += t;
            }
            if (lane < NW) waveSum[lane] = winc - wv;
        }
        __syncthreads();
        stv = inc - cntN + waveSum[wid];
        posc[tid] = stv;
    }

    // node outputs: dinv, y(q11), rowStart/rowCnt
    {
        int n = (b << NPB_SHIFT) + tid;
        if (n < N) {
            float di = rsqrtf(1.0f + (float)(dc & 0xFFFFFu) * INV11);
            dinv[n] = di;
            rowStart[n] = b * cap + stv;
            rowCnt[n] = cntN;
            float4 xv = x[n];
            s4 qv;
            qv.x = (short)__float2int_rn(xv.x * di * Q11);
            qv.y = (short)__float2int_rn(xv.y * di * Q11);
            qv.z = (short)__float2int_rn(xv.z * di * Q11);
            qv.w = (short)__float2int_rn(xv.w * di * Q11);
            y[n] = qv;
        }
    }
    __syncthreads();

    // pass 2: scatter dst-sorted (predicated; bin-local region, L2-absorbed)
    u64* dp = slotsB + (size_t)b * cap;
    for (int base = 0; base < c; base += CH) {
        int j = base + (tid << 3);
        u64 v[8];
        load8(sp, j, c, v);
#pragma unroll
        for (int q = 0; q < 8; ++q) {
            if (j + q < c) {
                int dl = (int)(((unsigned)v[q]) >> 23);
                int p = atomicAdd(&posc[dl], 1);
                dp[p] = v[q];
            }
        }
    }
}

// Thread-per-node layer1: register int accumulation + fused MLP.
__global__ __launch_bounds__(SORT_THREADS)
void k_layer1(const u64* __restrict__ slotsB, const int* __restrict__ rowStart,
              const int* __restrict__ rowCnt, const float* __restrict__ dinv,
              const s4* __restrict__ yq, const float* __restrict__ W1,
              const float* __restrict__ b1, const float* __restrict__ W2,
              float* __restrict__ z, int N) {
    __shared__ float sW1[64], sb1[16], sW2[16];
    if (threadIdx.x < 64) sW1[threadIdx.x] = W1[threadIdx.x];
    if (threadIdx.x < 16) {
        sb1[threadIdx.x] = b1[threadIdx.x];
        sW2[threadIdx.x] = W2[threadIdx.x];
    }
    __syncthreads();
    const int n = blockIdx.x * SORT_THREADS + threadIdx.x;
    if (n >= N) return;
    const u64* rp = slotsB + rowStart[n];
    const int cnt = rowCnt[n];
    int a0 = 0, a1 = 0, a2 = 0, a3 = 0;
    int j = 0;
    for (; j + 4 <= cnt; j += 4) {
        u64 v0 = rp[j], v1 = rp[j + 1], v2 = rp[j + 2], v3 = rp[j + 3];
        s4 g0 = yq[(unsigned)v0 & 0x7FFFFF];
        s4 g1 = yq[(unsigned)v1 & 0x7FFFFF];
        s4 g2 = yq[(unsigned)v2 & 0x7FFFFF];
        s4 g3 = yq[(unsigned)v3 & 0x7FFFFF];
        int w0 = (int)(v0 >> 32), w1 = (int)(v1 >> 32);
        int w2 = (int)(v2 >> 32), w3 = (int)(v3 >> 32);
        a0 += w0 * (int)g0.x + w1 * (int)g1.x + w2 * (int)g2.x + w3 * (int)g3.x;
        a1 += w0 * (int)g0.y + w1 * (int)g1.y + w2 * (int)g2.y + w3 * (int)g3.y;
        a2 += w0 * (int)g0.z + w1 * (int)g1.z + w2 * (int)g2.z + w3 * (int)g3.z;
        a3 += w0 * (int)g0.w + w1 * (int)g1.w + w2 * (int)g2.w + w3 * (int)g3.w;
    }
    for (; j < cnt; ++j) {
        u64 v = rp[j];
        s4 g = yq[(unsigned)v & 0x7FFFFF];
        int w = (int)(v >> 32);
        a0 += w * (int)g.x; a1 += w * (int)g.y;
        a2 += w * (int)g.z; a3 += w * (int)g.w;
    }
    const float di = dinv[n];
    s4 yv = yq[n];
    float ax = di * ((float)yv.x * INV11 + (float)a0 * A1_INV);
    float ay = di * ((float)yv.y * INV11 + (float)a1 * A1_INV);
    float az = di * ((float)yv.z * INV11 + (float)a2 * A1_INV);
    float aw = di * ((float)yv.w * INV11 + (float)a3 * A1_INV);
    float sacc = 0.0f;
#pragma unroll
    for (int k = 0; k < 16; ++k) {
        float h = ax * sW1[k] + ay * sW1[16 + k] + az * sW1[32 + k]
                + aw * sW1[48 + k] + sb1[k];
        sacc += fmaxf(h, 0.0f) * sW2[k];
    }
    z[n] = sacc * di;
}

// Thread-per-node layer2: register int accumulation (deterministic).
__global__ __launch_bounds__(SORT_THREADS)
void k_layer2(const u64* __restrict__ slotsB, const int* __restrict__ rowStart,
              const int* __restrict__ rowCnt, const float* __restrict__ dinv,
              const float* __restrict__ z, const float* __restrict__ b2,
              float* __restrict__ out, int N) {
    const int n = blockIdx.x * SORT_THREADS + threadIdx.x;
    if (n >= N) return;
    const u64* rp = slotsB + rowStart[n];
    const int cnt = rowCnt[n];
    int acc = 0;
    int j = 0;
    for (; j + 4 <= cnt; j += 4) {
        u64 v0 = rp[j], v1 = rp[j + 1], v2 = rp[j + 2], v3 = rp[j + 3];
        float z0 = z[(unsigned)v0 & 0x7FFFFF];
        float z1 = z[(unsigned)v1 & 0x7FFFFF];
        float z2 = z[(unsigned)v2 & 0x7FFFFF];
        float z3 = z[(unsigned)v3 & 0x7FFFFF];
        acc += __float2int_rn((float)(int)(v0 >> 32) * z0 * 512.0f)
             + __float2int_rn((float)(int)(v1 >> 32) * z1 * 512.0f)
             + __float2int_rn((float)(int)(v2 >> 32) * z2 * 512.0f)
             + __float2int_rn((float)(int)(v3 >> 32) * z3 * 512.0f);
    }
    for (; j < cnt; ++j) {
        u64 v = rp[j];
        acc += __float2int_rn((float)(int)(v >> 32) * z[(unsigned)v & 0x7FFFFF] * 512.0f);
    }
    const float di = dinv[n];
    out[n] = di * (z[n] + (float)acc * A2_INV) + b2[0];
}

// ------------------------- fallback (round-1) path -------------------------
__global__ __launch_bounds__(256)
void k_init(float* __restrict__ deg, int N) {
    int i = blockIdx.x * blockDim.x + threadIdx.x;
    if (i < N) deg[i] = 1.0f;
}

__global__ __launch_bounds__(256)
void k_deg(const void* __restrict__ idx, const float* __restrict__ ew,
           float* __restrict__ deg, int E, const int* __restrict__ flag) {
    const bool is64 = (*flag != 0);
    const int stride = gridDim.x * blockDim.x;
    for (int e = blockIdx.x * blockDim.x + threadIdx.x; e < E; e += stride) {
        int d = is64 ? (int)((const long long*)idx)[(long long)E + e]
                     : ((const int*)idx)[E + e];
        atomicAdd(deg + d, ew[e]);
    }
}

__global__ __launch_bounds__(256)
void k_dinv_accx(float* __restrict__ deg_dinv, const float4* __restrict__ x,
                 float4* __restrict__ accx, int N) {
    int n = blockIdx.x * blockDim.x + threadIdx.x;
    if (n >= N) return;
    float dg = deg_dinv[n];
    float di = (dg > 0.0f) ? rsqrtf(dg) : 0.0f;
    deg_dinv[n] = di;
    float sn = di * di;
    float4 xv = x[n];
    accx[n] = make_float4(xv.x * sn, xv.y * sn, xv.z * sn, xv.w * sn);
}

__global__ __launch_bounds__(256)
void k_scatter1(const void* __restrict__ idx, const float* __restrict__ ew,
                const float* __restrict__ dinv, const float4* __restrict__ x,
                float* __restrict__ accx, int E, const int* __restrict__ flag) {
    const bool is64 = (*flag != 0);
    const int stride = gridDim.x * blockDim.x;
    for (int e = blockIdx.x * blockDim.x + threadIdx.x; e < E; e += stride) {
        int s, d;
        if (is64) {
            const long long* p = (const long long*)idx;
            s = (int)p[e]; d = (int)p[(long long)E + e];
        } else {
            const int* p = (const int*)idx;
            s = p[e]; d = p[E + e];
        }
        float nm = dinv[s] * ew[e] * dinv[d];
        float4 xv = x[s];
        float* dp = accx + (size_t)d * 4;
        atomicAdd(dp + 0, nm * xv.x);
        atomicAdd(dp + 1, nm * xv.y);
        atomicAdd(dp + 2, nm * xv.z);
        atomicAdd(dp + 3, nm * xv.w);
    }
}

__global__ __launch_bounds__(256)
void k_node2(const float4* __restrict__ accx, const float* __restrict__ dinv,
             const float* __restrict__ W1, const float* __restrict__ b1,
             const float* __restrict__ W2, const float* __restrict__ b2,
             float* __restrict__ s2, float* __restrict__ out, int N) {
    __shared__ float sW1[64], sb1[16], sW2[16];
    if (threadIdx.x < 64) sW1[threadIdx.x] = W1[threadIdx.x];
    if (threadIdx.x < 16) {
        sb1[threadIdx.x] = b1[threadIdx.x];
        sW2[threadIdx.x] = W2[threadIdx.x];
    }
    __syncthreads();
    int n = blockIdx.x * blockDim.x + threadIdx.x;
    if (n >= N) return;
    float bb2 = b2[0];
    float4 a = accx[n];
    float acc = 0.0f;
#pragma unroll
    for (int k = 0; k < 16; ++k) {
        float h = a.x * sW1[k] + a.y * sW1[16 + k] + a.z * sW1[32 + k]
                + a.w * sW1[48 + k] + sb1[k];
        acc += fmaxf(h, 0.0f) * sW2[k];
    }
    s2[n] = acc;
    float di = dinv[n];
    out[n] = acc * di * di + bb2;
}

__global__ __launch_bounds__(256)
void k_scatter2(const void* __restrict__ idx, const float* __restrict__ ew,
                const float* __restrict__ dinv, const float* __restrict__ s2,
                float* __restrict__ out, int E, const int* __restrict__ flag) {
    const bool is64 = (*flag != 0);
    const int stride = gridDim.x * blockDim.x;
    for (int e = blockIdx.x * blockDim.x + threadIdx.x; e < E; e += stride) {
        int s, d;
        if (is64) {
            const long long* p = (const long long*)idx;
            s = (int)p[e]; d = (int)p[(long long)E + e];
        } else {
            const int* p = (const int*)idx;
            s = p[e]; d = p[E + e];
        }
        float nm = dinv[s] * ew[e] * dinv[d];
        atomicAdd(out + d, nm * s2[s]);
    }
}

// ---------------------------------------------------------------------------
extern "C" void kernel_launch(void* const* d_in, const int* in_sizes, int n_in,
                              void* d_out, int out_size, void* d_ws, size_t ws_size,
                              hipStream_t stream) {
    const float* x   = (const float*)d_in[0];
    const void*  eix = d_in[1];
    const float* ew  = (const float*)d_in[2];
    const float* W1  = (const float*)d_in[3];
    const float* b1  = (const float*)d_in[4];
    const float* W2  = (const float*)d_in[5];
    const float* b2  = (const float*)d_in[6];
    float* out = (float*)d_out;

    const int N = in_sizes[0] / 4;   // x is [N,4]
    const int E = in_sizes[2];       // edge_weight is [E]

    const int B = (N + NPB - 1) >> NPB_SHIFT;
    int cap = (E / B + 2048 + 7) & ~7;   // mean + ~23 sigma, multiple of 8
    const int nCheck = (E < 65536) ? E : 65536;

    // ws: y s4[N] | slotsA u64[B*cap] | slotsB u64[B*cap] | gCnt[B]
    //   | rowStart[N] | rowCnt[N] | dinv[N] | z[N] | flag
    size_t need = (size_t)N * 8 + 2 * (size_t)B * cap * 8
                + (size_t)B * 4 + (size_t)N * 16 + 256;

    bool addr32ok = ((long long)B * cap) < 0xFFFFFFFFLL;

    if (B <= MAX_BINS && N < (1 << 23) && ws_size >= need && addr32ok) {
        s4* y = (s4*)d_ws;
        u64* slotsA = (u64*)(y + N);
        u64* slotsB = slotsA + (size_t)B * cap;
        int*   gCnt = (int*)(slotsB + (size_t)B * cap);
        int*   rowStart = gCnt + B;
        int*   rowCnt   = rowStart + N;
        float* dinv = (float*)(rowCnt + N);
        float* z    = dinv + N;
        int*   flag = (int*)(z + N);

        const int part_blocks = (E + PART_CHUNK - 1) / PART_CHUNK;

        k_zero<<<(B + 255) / 256, 256, 0, stream>>>(gCnt, B);
        k_detect<<<1, 1024, 0, stream>>>((const unsigned int*)eix, nCheck, flag);
        k_partition<<<part_blocks, PART_THREADS, 0, stream>>>(eix, ew, gCnt, slotsA,
                                                              E, B, cap, flag);
        k_sort<<<B, SORT_THREADS, 0, stream>>>(slotsA, gCnt, (const float4*)x,
                                               slotsB, rowStart, rowCnt, dinv, y,
                                               N, cap);
        k_layer1<<<B, SORT_THREADS, 0, stream>>>(slotsB, rowStart, rowCnt, dinv,
                                                 y, W1, b1, W2, z, N);
        k_layer2<<<B, SORT_THREADS, 0, stream>>>(slotsB, rowStart, rowCnt, dinv,
                                                 z, b2, out, N);
    } else {
        // fallback: direct atomic scatter (round-1)
        const int nb_n = (N + 255) / 256;
        const int nb_e = min((E + 255) / 256, 16384);
        float* deg  = (float*)d_ws;
        float* accx = deg + N;
        float* s2   = accx + (size_t)4 * N;
        int*   flag = (int*)(s2 + N);

        k_init<<<nb_n, 256, 0, stream>>>(deg, N);
        k_detect<<<1, 1024, 0, stream>>>((const unsigned int*)eix, nCheck, flag);
        k_deg<<<nb_e, 256, 0, stream>>>(eix, ew, deg, E, flag);
        k_dinv_accx<<<nb_n, 256, 0, stream>>>(deg, (const float4*)x, (float4*)accx, N);
        k_scatter1<<<nb_e, 256, 0, stream>>>(eix, ew, deg, (const float4*)x, accx, E, flag);
        k_node2<<<nb_n, 256, 0, stream>>>((const float4*)accx, deg, W1, b1, W2, b2, s2, out, N);
        k_scatter2<<<nb_e, 256, 0, stream>>>(eix, ew, deg, s2, out, E, flag);
    }
}

// Round 16
// 254.278 us; speedup vs baseline: 1.2601x; 1.2601x over previous
//
#include <hip/hip_runtime.h>
#include <hip/hip_fp16.h>

// ---------------------------------------------------------------------------
// CrowdGNN: 2-layer GCN, N=500k nodes, E=8M edges (+ implicit self loops).
// Round-16 = round-8 champion (242.5us) + NON-TEMPORAL slot-stream loads in
// the agg kernels. Theory: the read-once 64MB slot stream evicts the 4MB
// fp16 y table (and 2MB z) from per-XCD L2 -> per-edge gathers miss L2 and
// bottleneck on the L3 random-access path (~80-92us across three layer1
// structures; CSR variant showed 235MB of 32B gather sectors in FETCH).
// nt loads mark stream lines evict-first, preserving L2 for the tables.
// Structure: partition (bin dst>>9, LDS bin-sorted staged coalesced writes)
//   -> deg/dinv/y (int fixed-point LDS atomics, native ds_add)
//   -> layer1 (4-wide slot loop, h4 gathers, int LDS atomics, fused MLP)
//   -> layer2 (z gathers, int LDS atomics).
// ---------------------------------------------------------------------------

typedef unsigned long long u64;
typedef long long ll2 __attribute__((ext_vector_type(2)));
typedef float f4 __attribute__((ext_vector_type(4)));

#define NPB_SHIFT 9
#define NPB 512
#define MAX_BINS 1024
#define PART_THREADS 1024
#define PART_EPT 4
#define PART_CHUNK (PART_THREADS * PART_EPT)   // 4096 edges per block
#define AGG_THREADS 512

#define DEG_SCALE  16777216.0f   // 2^24
#define DEG_INV    (1.0f / 16777216.0f)
#define A1_SCALE   4194304.0f    // 2^22
#define A1_INV     (1.0f / 4194304.0f)
#define A2_SCALE   1048576.0f    // 2^20
#define A2_INV     (1.0f / 1048576.0f)

struct h4 { __half2 a, b; };

__device__ __forceinline__ float4 h4_to_f4(h4 v) {
    float2 lo = __half22float2(v.a);
    float2 hi = __half22float2(v.b);
    return make_float4(lo.x, lo.y, hi.x, hi.y);
}

// Detect int64 vs int32 edge_index: int64 values < 2^31 => odd words all zero.
__global__ __launch_bounds__(1024)
void k_detect(const unsigned int* __restrict__ idx_words, int nCheck, int* flag) {
    __shared__ int cnt;
    if (threadIdx.x == 0) cnt = 0;
    __syncthreads();
    int local = 0;
    for (int i = threadIdx.x; i < nCheck; i += blockDim.x)
        local += (idx_words[2 * i + 1] != 0u) ? 1 : 0;
    if (local) atomicAdd(&cnt, local);
    __syncthreads();
    if (threadIdx.x == 0) *flag = (cnt < 8) ? 1 : 0;
}

__global__ __launch_bounds__(256)
void k_zero(int* __restrict__ p, int n) {
    int i = blockIdx.x * blockDim.x + threadIdx.x;
    if (i < n) p[i] = 0;
}

// Bin-sorted-staging partition (round-8, unchanged).
__global__ __launch_bounds__(PART_THREADS)
void k_partition(const void* __restrict__ idx, const float* __restrict__ ew,
                 int* __restrict__ gCnt, u64* __restrict__ slots,
                 int E, int B, int cap, const int* __restrict__ flag) {
    __shared__ int lcnt[MAX_BINS];
    __shared__ int lbase[MAX_BINS];
    __shared__ int lstart[MAX_BINS];
    __shared__ u64 sPay[PART_CHUNK];
    __shared__ unsigned sAddr[PART_CHUNK];
    __shared__ int waveSum[PART_THREADS / 64];

    const bool is64 = (*flag != 0);
    const int tid = threadIdx.x;
    for (int i = tid; i < MAX_BINS; i += PART_THREADS) lcnt[i] = 0;
    __syncthreads();

    const int base_e = blockIdx.x * PART_CHUNK;
    const int nValid = min(PART_CHUNK, E - base_e);

    u64 pay[PART_EPT];
    int bin_[PART_EPT], r_[PART_EPT];
#pragma unroll
    for (int i = 0; i < PART_EPT; ++i) {
        int e = base_e + i * PART_THREADS + tid;
        bin_[i] = -1;
        if (e < E) {
            int s, d;
            if (is64) {
                const long long* p = (const long long*)idx;
                s = (int)__builtin_nontemporal_load(p + e);
                d = (int)__builtin_nontemporal_load(p + (long long)E + e);
            } else {
                const int* p = (const int*)idx;
                s = __builtin_nontemporal_load(p + e);
                d = __builtin_nontemporal_load(p + E + e);
            }
            float w = __builtin_nontemporal_load(ew + e);
            int bin = d >> NPB_SHIFT;
            unsigned pk = ((unsigned)(d & (NPB - 1)) << 23) | (unsigned)s;
            pay[i] = ((u64)__float_as_uint(w) << 32) | pk;
            bin_[i] = bin;
            r_[i] = atomicAdd(&lcnt[bin], 1);
        }
    }
    __syncthreads();

    {
        const int lane = tid & 63, wid = tid >> 6;
        const int v = lcnt[tid];
        int inc = v;
#pragma unroll
        for (int off = 1; off < 64; off <<= 1) {
            int t = __shfl_up(inc, off, 64);
            if (lane >= off) inc += t;
        }
        if (lane == 63) waveSum[wid] = inc;
        __syncthreads();
        if (wid == 0) {
            const int NW = PART_THREADS / 64;
            int wv = (lane < NW) ? waveSum[lane] : 0;
            int winc = wv;
#pragma unroll
            for (int off = 1; off < NW; off <<= 1) {
                int t = __shfl_up(winc, off, 64);
                if (lane >= off) winc += t;
            }
            if (lane < NW) waveSum[lane] = winc - wv;
        }
        __syncthreads();
        lstart[tid] = inc - v + waveSum[wid];
        lbase[tid] = (v > 0 && tid < B) ? atomicAdd(&gCnt[tid], v) : 0;
    }
    __syncthreads();

#pragma unroll
    for (int i = 0; i < PART_EPT; ++i) {
        if (bin_[i] >= 0) {
            int si = lstart[bin_[i]] + r_[i];
            long long pos = (long long)lbase[bin_[i]] + r_[i];
            sPay[si] = pay[i];
            sAddr[si] = (pos < cap)
                      ? (unsigned)((long long)bin_[i] * cap + pos)
                      : 0xFFFFFFFFu;
        }
    }
    __syncthreads();

    for (int k = tid; k < nValid; k += PART_THREADS) {
        unsigned a = sAddr[k];
        if (a != 0xFFFFFFFFu) slots[a] = sPay[k];
    }
}

// 4-wide slot fetch with sentinel-0 fill (w=0 -> no-op adds).
// NON-TEMPORAL: the stream is read-once; evict-first keeps the y/z tables
// resident in per-XCD L2 (the whole point of this round).
__device__ __forceinline__ void load4(const u64* __restrict__ sp, int j, int c,
                                      u64& v0, u64& v1, u64& v2, u64& v3) {
    v0 = v1 = v2 = v3 = 0;
    if (j + 3 < c) {
        ll2 q0 = __builtin_nontemporal_load((const ll2*)(sp + j));
        ll2 q1 = __builtin_nontemporal_load((const ll2*)(sp + j) + 1);
        v0 = (u64)q0.x; v1 = (u64)q0.y; v2 = (u64)q1.x; v3 = (u64)q1.y;
    } else if (j < c) {
        v0 = __builtin_nontemporal_load(sp + j);
        if (j + 1 < c) v1 = __builtin_nontemporal_load(sp + j + 1);
        if (j + 2 < c) v2 = __builtin_nontemporal_load(sp + j + 2);
    }
}

// Per-bin: deg[n] = 1 + sum w; dinv = rsqrt(deg); y[n] = fp16(x[n]*dinv).
// Fixed-point int accumulation (native ds_add_u32).
__global__ __launch_bounds__(AGG_THREADS, 4)
void k_deg_dinv(const u64* __restrict__ slots, const int* __restrict__ gCnt,
                const float* __restrict__ x, float* __restrict__ dinv,
                h4* __restrict__ y, int N, int cap) {
    __shared__ int degLds[NPB];
    const int b = blockIdx.x;
    for (int t = threadIdx.x; t < NPB; t += AGG_THREADS) degLds[t] = 0;
    __syncthreads();
    const int c = min(gCnt[b], cap);
    const u64* sp = slots + (size_t)b * cap;
    const int CH = AGG_THREADS * 4;
    for (int base = 0; base < c; base += CH) {
        int j = base + (threadIdx.x << 2);
        u64 v0, v1, v2, v3;
        load4(sp, j, c, v0, v1, v2, v3);
        atomicAdd(&degLds[((unsigned)v0) >> 23],
                  __float2int_rn(__uint_as_float((unsigned)(v0 >> 32)) * DEG_SCALE));
        atomicAdd(&degLds[((unsigned)v1) >> 23],
                  __float2int_rn(__uint_as_float((unsigned)(v1 >> 32)) * DEG_SCALE));
        atomicAdd(&degLds[((unsigned)v2) >> 23],
                  __float2int_rn(__uint_as_float((unsigned)(v2 >> 32)) * DEG_SCALE));
        atomicAdd(&degLds[((unsigned)v3) >> 23],
                  __float2int_rn(__uint_as_float((unsigned)(v3 >> 32)) * DEG_SCALE));
    }
    __syncthreads();
    for (int t = threadIdx.x; t < NPB; t += AGG_THREADS) {
        int n = (b << NPB_SHIFT) + t;
        if (n < N) {
            float deg = 1.0f + (float)degLds[t] * DEG_INV;
            float di = rsqrtf(deg);
            dinv[n] = di;
            f4 xv = __builtin_nontemporal_load((const f4*)x + n);  // read-once
            h4 hv;
            hv.a = __floats2half2_rn(xv.x * di, xv.y * di);
            hv.b = __floats2half2_rn(xv.z * di, xv.w * di);
            y[n] = hv;
        }
    }
}

// Per-bin layer1 aggregation + fused MLP: z[n] = dinv[n]*MLP(di*(y[n]+sum w*y[s]))
__global__ __launch_bounds__(AGG_THREADS, 4)
void k_layer1(const u64* __restrict__ slots, const int* __restrict__ gCnt,
              const float* __restrict__ dinv, const h4* __restrict__ yh,
              const float* __restrict__ W1, const float* __restrict__ b1,
              const float* __restrict__ W2, float* __restrict__ z,
              int N, int cap) {
    __shared__ int acc[NPB][5];   // stride 5 -> 32-bank spread; int fixed-point
    __shared__ float dLds[NPB];
    __shared__ float sW1[64], sb1[16], sW2[16];
    if (threadIdx.x < 64) sW1[threadIdx.x] = W1[threadIdx.x];
    if (threadIdx.x < 16) {
        sb1[threadIdx.x] = b1[threadIdx.x];
        sW2[threadIdx.x] = W2[threadIdx.x];
    }
    const int b = blockIdx.x;
    for (int t = threadIdx.x; t < NPB; t += AGG_THREADS) {
        acc[t][0] = acc[t][1] = acc[t][2] = acc[t][3] = 0;
        int n = (b << NPB_SHIFT) + t;
        dLds[t] = (n < N) ? dinv[n] : 0.0f;
    }
    __syncthreads();
    const int c = min(gCnt[b], cap);
    const u64* sp = slots + (size_t)b * cap;
    const int CH = AGG_THREADS * 4;
    for (int base = 0; base < c; base += CH) {
        int j = base + (threadIdx.x << 2);
        u64 v0, v1, v2, v3;
        load4(sp, j, c, v0, v1, v2, v3);
        unsigned pk0 = (unsigned)v0, pk1 = (unsigned)v1,
                 pk2 = (unsigned)v2, pk3 = (unsigned)v3;
        float w0 = __uint_as_float((unsigned)(v0 >> 32));
        float w1 = __uint_as_float((unsigned)(v1 >> 32));
        float w2 = __uint_as_float((unsigned)(v2 >> 32));
        float w3 = __uint_as_float((unsigned)(v3 >> 32));
        // 4 independent CACHED gathers from the (now L2-resident) y table
        h4 g0 = yh[pk0 & 0x7FFFFF];
        h4 g1 = yh[pk1 & 0x7FFFFF];
        h4 g2 = yh[pk2 & 0x7FFFFF];
        h4 g3 = yh[pk3 & 0x7FFFFF];
        float4 f0 = h4_to_f4(g0), f1 = h4_to_f4(g1),
               f2 = h4_to_f4(g2), f3 = h4_to_f4(g3);
        int d0 = pk0 >> 23, d1 = pk1 >> 23, d2 = pk2 >> 23, d3 = pk3 >> 23;
        atomicAdd(&acc[d0][0], __float2int_rn(w0 * f0.x * A1_SCALE));
        atomicAdd(&acc[d0][1], __float2int_rn(w0 * f0.y * A1_SCALE));
        atomicAdd(&acc[d0][2], __float2int_rn(w0 * f0.z * A1_SCALE));
        atomicAdd(&acc[d0][3], __float2int_rn(w0 * f0.w * A1_SCALE));
        atomicAdd(&acc[d1][0], __float2int_rn(w1 * f1.x * A1_SCALE));
        atomicAdd(&acc[d1][1], __float2int_rn(w1 * f1.y * A1_SCALE));
        atomicAdd(&acc[d1][2], __float2int_rn(w1 * f1.z * A1_SCALE));
        atomicAdd(&acc[d1][3], __float2int_rn(w1 * f1.w * A1_SCALE));
        atomicAdd(&acc[d2][0], __float2int_rn(w2 * f2.x * A1_SCALE));
        atomicAdd(&acc[d2][1], __float2int_rn(w2 * f2.y * A1_SCALE));
        atomicAdd(&acc[d2][2], __float2int_rn(w2 * f2.z * A1_SCALE));
        atomicAdd(&acc[d2][3], __float2int_rn(w2 * f2.w * A1_SCALE));
        atomicAdd(&acc[d3][0], __float2int_rn(w3 * f3.x * A1_SCALE));
        atomicAdd(&acc[d3][1], __float2int_rn(w3 * f3.y * A1_SCALE));
        atomicAdd(&acc[d3][2], __float2int_rn(w3 * f3.z * A1_SCALE));
        atomicAdd(&acc[d3][3], __float2int_rn(w3 * f3.w * A1_SCALE));
    }
    __syncthreads();
    for (int t = threadIdx.x; t < NPB; t += AGG_THREADS) {
        int n = (b << NPB_SHIFT) + t;
        if (n >= N) continue;
        float di = dLds[t];
        float4 yv = h4_to_f4(yh[n]);
        float ax = di * (yv.x + (float)acc[t][0] * A1_INV);
        float ay = di * (yv.y + (float)acc[t][1] * A1_INV);
        float az = di * (yv.z + (float)acc[t][2] * A1_INV);
        float aw = di * (yv.w + (float)acc[t][3] * A1_INV);
        float sacc = 0.0f;
#pragma unroll
        for (int k = 0; k < 16; ++k) {
            float h = ax * sW1[k] + ay * sW1[16 + k] + az * sW1[32 + k]
                    + aw * sW1[48 + k] + sb1[k];
            sacc += fmaxf(h, 0.0f) * sW2[k];
        }
        z[n] = sacc * di;
    }
}

// Per-bin layer2: out[n] = di*(z[n] + sum w*z[s]) + b2
__global__ __launch_bounds__(AGG_THREADS, 4)
void k_layer2(const u64* __restrict__ slots, const int* __restrict__ gCnt,
              const float* __restrict__ dinv, const float* __restrict__ z,
              const float* __restrict__ b2, float* __restrict__ out,
              int N, int cap) {
    __shared__ int accs[NPB];
    __shared__ float dLds[NPB];
    const int b = blockIdx.x;
    for (int t = threadIdx.x; t < NPB; t += AGG_THREADS) {
        accs[t] = 0;
        int n = (b << NPB_SHIFT) + t;
        dLds[t] = (n < N) ? dinv[n] : 0.0f;
    }
    __syncthreads();
    const int c = min(gCnt[b], cap);
    const u64* sp = slots + (size_t)b * cap;
    const int CH = AGG_THREADS * 4;
    for (int base = 0; base < c; base += CH) {
        int j = base + (threadIdx.x << 2);
        u64 v0, v1, v2, v3;
        load4(sp, j, c, v0, v1, v2, v3);
        unsigned pk0 = (unsigned)v0, pk1 = (unsigned)v1,
                 pk2 = (unsigned)v2, pk3 = (unsigned)v3;
        float z0 = z[pk0 & 0x7FFFFF];   // cached gathers (L2-resident z)
        float z1 = z[pk1 & 0x7FFFFF];
        float z2 = z[pk2 & 0x7FFFFF];
        float z3 = z[pk3 & 0x7FFFFF];
        atomicAdd(&accs[pk0 >> 23],
                  __float2int_rn(__uint_as_float((unsigned)(v0 >> 32)) * z0 * A2_SCALE));
        atomicAdd(&accs[pk1 >> 23],
                  __float2int_rn(__uint_as_float((unsigned)(v1 >> 32)) * z1 * A2_SCALE));
        atomicAdd(&accs[pk2 >> 23],
                  __float2int_rn(__uint_as_float((unsigned)(v2 >> 32)) * z2 * A2_SCALE));
        atomicAdd(&accs[pk3 >> 23],
                  __float2int_rn(__uint_as_float((unsigned)(v3 >> 32)) * z3 * A2_SCALE));
    }
    __syncthreads();
    const float bb2 = b2[0];
    for (int t = threadIdx.x; t < NPB; t += AGG_THREADS) {
        int n = (b << NPB_SHIFT) + t;
        if (n < N) out[n] = dLds[t] * (z[n] + (float)accs[t] * A2_INV) + bb2;
    }
}

// ------------------------- fallback (round-1) path -------------------------
__global__ __launch_bounds__(256)
void k_init(float* __restrict__ deg, int N) {
    int i = blockIdx.x * blockDim.x + threadIdx.x;
    if (i < N) deg[i] = 1.0f;
}

__global__ __launch_bounds__(256)
void k_deg(const void* __restrict__ idx, const float* __restrict__ ew,
           float* __restrict__ deg, int E, const int* __restrict__ flag) {
    const bool is64 = (*flag != 0);
    const int stride = gridDim.x * blockDim.x;
    for (int e = blockIdx.x * blockDim.x + threadIdx.x; e < E; e += stride) {
        int d = is64 ? (int)((const long long*)idx)[(long long)E + e]
                     : ((const int*)idx)[E + e];
        atomicAdd(deg + d, ew[e]);
    }
}

__global__ __launch_bounds__(256)
void k_dinv_accx(float* __restrict__ deg_dinv, const float4* __restrict__ x,
                 float4* __restrict__ accx, int N) {
    int n = blockIdx.x * blockDim.x + threadIdx.x;
    if (n >= N) return;
    float dg = deg_dinv[n];
    float di = (dg > 0.0f) ? rsqrtf(dg) : 0.0f;
    deg_dinv[n] = di;
    float sn = di * di;
    float4 xv = x[n];
    accx[n] = make_float4(xv.x * sn, xv.y * sn, xv.z * sn, xv.w * sn);
}

__global__ __launch_bounds__(256)
void k_scatter1(const void* __restrict__ idx, const float* __restrict__ ew,
                const float* __restrict__ dinv, const float4* __restrict__ x,
                float* __restrict__ accx, int E, const int* __restrict__ flag) {
    const bool is64 = (*flag != 0);
    const int stride = gridDim.x * blockDim.x;
    for (int e = blockIdx.x * blockDim.x + threadIdx.x; e < E; e += stride) {
        int s, d;
        if (is64) {
            const long long* p = (const long long*)idx;
            s = (int)p[e]; d = (int)p[(long long)E + e];
        } else {
            const int* p = (const int*)idx;
            s = p[e]; d = p[E + e];
        }
        float nm = dinv[s] * ew[e] * dinv[d];
        float4 xv = x[s];
        float* dp = accx + (size_t)d * 4;
        atomicAdd(dp + 0, nm * xv.x);
        atomicAdd(dp + 1, nm * xv.y);
        atomicAdd(dp + 2, nm * xv.z);
        atomicAdd(dp + 3, nm * xv.w);
    }
}

__global__ __launch_bounds__(256)
void k_node2(const float4* __restrict__ accx, const float* __restrict__ dinv,
             const float* __restrict__ W1, const float* __restrict__ b1,
             const float* __restrict__ W2, const float* __restrict__ b2,
             float* __restrict__ s2, float* __restrict__ out, int N) {
    __shared__ float sW1[64], sb1[16], sW2[16];
    if (threadIdx.x < 64) sW1[threadIdx.x] = W1[threadIdx.x];
    if (threadIdx.x < 16) {
        sb1[threadIdx.x] = b1[threadIdx.x];
        sW2[threadIdx.x] = W2[threadIdx.x];
    }
    __syncthreads();
    int n = blockIdx.x * blockDim.x + threadIdx.x;
    if (n >= N) return;
    float bb2 = b2[0];
    float4 a = accx[n];
    float acc = 0.0f;
#pragma unroll
    for (int k = 0; k < 16; ++k) {
        float h = a.x * sW1[k] + a.y * sW1[16 + k] + a.z * sW1[32 + k]
                + a.w * sW1[48 + k] + sb1[k];
        acc += fmaxf(h, 0.0f) * sW2[k];
    }
    s2[n] = acc;
    float di = dinv[n];
    out[n] = acc * di * di + bb2;
}

__global__ __launch_bounds__(256)
void k_scatter2(const void* __restrict__ idx, const float* __restrict__ ew,
                const float* __restrict__ dinv, const float* __restrict__ s2,
                float* __restrict__ out, int E, const int* __restrict__ flag) {
    const bool is64 = (*flag != 0);
    const int stride = gridDim.x * blockDim.x;
    for (int e = blockIdx.x * blockDim.x + threadIdx.x; e < E; e += stride) {
        int s, d;
        if (is64) {
            const long long* p = (const long long*)idx;
            s = (int)p[e]; d = (int)p[(long long)E + e];
        } else {
            const int* p = (const int*)idx;
            s = p[e]; d = p[E + e];
        }
        float nm = dinv[s] * ew[e] * dinv[d];
        atomicAdd(out + d, nm * s2[s]);
    }
}

// ---------------------------------------------------------------------------
extern "C" void kernel_launch(void* const* d_in, const int* in_sizes, int n_in,
                              void* d_out, int out_size, void* d_ws, size_t ws_size,
                              hipStream_t stream) {
    const float* x   = (const float*)d_in[0];
    const void*  eix = d_in[1];
    const float* ew  = (const float*)d_in[2];
    const float* W1  = (const float*)d_in[3];
    const float* b1  = (const float*)d_in[4];
    const float* W2  = (const float*)d_in[5];
    const float* b2  = (const float*)d_in[6];
    float* out = (float*)d_out;

    const int N = in_sizes[0] / 4;   // x is [N,4]
    const int E = in_sizes[2];       // edge_weight is [E]

    const int B = (N + NPB - 1) >> NPB_SHIFT;
    int cap = (E / B + 2048 + 3) & ~3;   // mean + ~23 sigma, multiple of 4
    const int nCheck = (E < 65536) ? E : 65536;

    // ws: y [N h4=8B] | slots [B*cap u64] | gCnt [B] | dinv [N] | z [N] | flag
    size_t need = (size_t)N * 8 + (size_t)B * cap * 8
                + (size_t)B * 4 + (size_t)N * 8 + 256;

    bool addr32ok = ((long long)B * cap) < 0xFFFFFFFFLL;

    if (B <= MAX_BINS && N < (1 << 23) && ws_size >= need && addr32ok) {
        h4* y = (h4*)d_ws;
        u64* slots = (u64*)(y + N);
        int*   gCnt = (int*)(slots + (size_t)B * cap);
        float* dinv = (float*)(gCnt + B);
        float* z    = dinv + N;
        int*   flag = (int*)(z + N);

        const int part_blocks = (E + PART_CHUNK - 1) / PART_CHUNK;

        k_zero<<<(B + 255) / 256, 256, 0, stream>>>(gCnt, B);
        k_detect<<<1, 1024, 0, stream>>>((const unsigned int*)eix, nCheck, flag);
        k_partition<<<part_blocks, PART_THREADS, 0, stream>>>(eix, ew, gCnt, slots,
                                                              E, B, cap, flag);
        k_deg_dinv<<<B, AGG_THREADS, 0, stream>>>(slots, gCnt, x, dinv, y, N, cap);
        k_layer1<<<B, AGG_THREADS, 0, stream>>>(slots, gCnt, dinv, y, W1, b1, W2,
                                                z, N, cap);
        k_layer2<<<B, AGG_THREADS, 0, stream>>>(slots, gCnt, dinv, z, b2, out, N, cap);
    } else {
        // fallback: direct atomic scatter (round-1)
        const int nb_n = (N + 255) / 256;
        const int nb_e = min((E + 255) / 256, 16384);
        float* deg  = (float*)d_ws;
        float* accx = deg + N;
        float* s2   = accx + (size_t)4 * N;
        int*   flag = (int*)(s2 + N);

        k_init<<<nb_n, 256, 0, stream>>>(deg, N);
        k_detect<<<1, 1024, 0, stream>>>((const unsigned int*)eix, nCheck, flag);
        k_deg<<<nb_e, 256, 0, stream>>>(eix, ew, deg, E, flag);
        k_dinv_accx<<<nb_n, 256, 0, stream>>>(deg, (const float4*)x, (float4*)accx, N);
        k_scatter1<<<nb_e, 256, 0, stream>>>(eix, ew, deg, (const float4*)x, accx, E, flag);
        k_node2<<<nb_n, 256, 0, stream>>>((const float4*)accx, deg, W1, b1, W2, b2, s2, out, N);
        k_scatter2<<<nb_e, 256, 0, stream>>>(eix, ew, deg, s2, out, E, flag);
    }
}

// Round 17
// 227.195 us; speedup vs baseline: 1.4103x; 1.1192x over previous
//
#include <hip/hip_runtime.h>
#include <hip/hip_fp16.h>

// ---------------------------------------------------------------------------
// CrowdGNN: 2-layer GCN, N=500k nodes, E=8M edges (+ implicit self loops).
// Round-17 = round-8 champion (242.5us, cached loads — nt A/B showed nt costs
// ~12us, reverted) + HALVED layer1 LDS atomics via u64 packing:
//   - slot carries wq q11 (11-bit) instead of float w.
//   - deg pass packs (1<<20)|wq per edge -> weighted degree AND exact count;
//     count stored to rowCnt[N]. Predicated (no phantom counts).
//   - layer1 accumulates channel pairs in u64 LDS atomics (ds_add_u64),
//     2/edge instead of 4. Per-edge bias B=2^25 on each 32b field keeps all
//     partial sums in [0,2^32) -> no cross-field carry (|c|<=2^24.4<B;
//     cnt<=78 w.p. 1-1e-30 => sum<2^32). Epilogue: a = field - cnt*B.
//   - layer2 unchanged (already 1 atomic/edge), w = wq*INV11.
// Model being tested: LDS atomic throughput ~1 lane-atomic/cyc/CU is the
// agg-phase floor; halving layer1's atomics should cut ~26us.
// ---------------------------------------------------------------------------

typedef unsigned long long u64;
typedef long long ll2 __attribute__((ext_vector_type(2)));

#define NPB_SHIFT 9
#define NPB 512
#define MAX_BINS 1024
#define PART_THREADS 1024
#define PART_EPT 4
#define PART_CHUNK (PART_THREADS * PART_EPT)   // 4096 edges per block
#define AGG_THREADS 512

#define Q11      2048.0f
#define INV11    (1.0f / 2048.0f)
#define A1_INV   (1.0f / 4194304.0f)   // q22
#define A2_INV   (1.0f / 1048576.0f)   // q20
#define BIAS     (1u << 25)            // per-edge field bias, > max|c|=2^24.4

struct h4 { __half2 a, b; };

__device__ __forceinline__ float4 h4_to_f4(h4 v) {
    float2 lo = __half22float2(v.a);
    float2 hi = __half22float2(v.b);
    return make_float4(lo.x, lo.y, hi.x, hi.y);
}

// Detect int64 vs int32 edge_index: int64 values < 2^31 => odd words all zero.
__global__ __launch_bounds__(1024)
void k_detect(const unsigned int* __restrict__ idx_words, int nCheck, int* flag) {
    __shared__ int cnt;
    if (threadIdx.x == 0) cnt = 0;
    __syncthreads();
    int local = 0;
    for (int i = threadIdx.x; i < nCheck; i += blockDim.x)
        local += (idx_words[2 * i + 1] != 0u) ? 1 : 0;
    if (local) atomicAdd(&cnt, local);
    __syncthreads();
    if (threadIdx.x == 0) *flag = (cnt < 8) ? 1 : 0;
}

__global__ __launch_bounds__(256)
void k_zero(int* __restrict__ p, int n) {
    int i = blockIdx.x * blockDim.x + threadIdx.x;
    if (i < n) p[i] = 0;
}

// Bin-sorted-staging partition (round-8 structure; payload carries wq q11).
__global__ __launch_bounds__(PART_THREADS)
void k_partition(const void* __restrict__ idx, const float* __restrict__ ew,
                 int* __restrict__ gCnt, u64* __restrict__ slots,
                 int E, int B, int cap, const int* __restrict__ flag) {
    __shared__ int lcnt[MAX_BINS];
    __shared__ int lbase[MAX_BINS];
    __shared__ int lstart[MAX_BINS];
    __shared__ u64 sPay[PART_CHUNK];
    __shared__ unsigned sAddr[PART_CHUNK];
    __shared__ int waveSum[PART_THREADS / 64];

    const bool is64 = (*flag != 0);
    const int tid = threadIdx.x;
    for (int i = tid; i < MAX_BINS; i += PART_THREADS) lcnt[i] = 0;
    __syncthreads();

    const int base_e = blockIdx.x * PART_CHUNK;
    const int nValid = min(PART_CHUNK, E - base_e);

    u64 pay[PART_EPT];
    int bin_[PART_EPT], r_[PART_EPT];
#pragma unroll
    for (int i = 0; i < PART_EPT; ++i) {
        int e = base_e + i * PART_THREADS + tid;
        bin_[i] = -1;
        if (e < E) {
            int s, d;
            if (is64) {
                const long long* p = (const long long*)idx;
                s = (int)__builtin_nontemporal_load(p + e);
                d = (int)__builtin_nontemporal_load(p + (long long)E + e);
            } else {
                const int* p = (const int*)idx;
                s = __builtin_nontemporal_load(p + e);
                d = __builtin_nontemporal_load(p + E + e);
            }
            float w = __builtin_nontemporal_load(ew + e);
            int bin = d >> NPB_SHIFT;
            unsigned wq = min((unsigned)__float2int_rn(w * Q11), 2047u);
            unsigned pk = ((unsigned)(d & (NPB - 1)) << 23) | (unsigned)s;
            pay[i] = ((u64)wq << 32) | pk;
            bin_[i] = bin;
            r_[i] = atomicAdd(&lcnt[bin], 1);
        }
    }
    __syncthreads();

    {
        const int lane = tid & 63, wid = tid >> 6;
        const int v = lcnt[tid];
        int inc = v;
#pragma unroll
        for (int off = 1; off < 64; off <<= 1) {
            int t = __shfl_up(inc, off, 64);
            if (lane >= off) inc += t;
        }
        if (lane == 63) waveSum[wid] = inc;
        __syncthreads();
        if (wid == 0) {
            const int NW = PART_THREADS / 64;
            int wv = (lane < NW) ? waveSum[lane] : 0;
            int winc = wv;
#pragma unroll
            for (int off = 1; off < NW; off <<= 1) {
                int t = __shfl_up(winc, off, 64);
                if (lane >= off) winc += t;
            }
            if (lane < NW) waveSum[lane] = winc - wv;
        }
        __syncthreads();
        lstart[tid] = inc - v + waveSum[wid];
        lbase[tid] = (v > 0 && tid < B) ? atomicAdd(&gCnt[tid], v) : 0;
    }
    __syncthreads();

#pragma unroll
    for (int i = 0; i < PART_EPT; ++i) {
        if (bin_[i] >= 0) {
            int si = lstart[bin_[i]] + r_[i];
            long long pos = (long long)lbase[bin_[i]] + r_[i];
            sPay[si] = pay[i];
            sAddr[si] = (pos < cap)
                      ? (unsigned)((long long)bin_[i] * cap + pos)
                      : 0xFFFFFFFFu;
        }
    }
    __syncthreads();

    for (int k = tid; k < nValid; k += PART_THREADS) {
        unsigned a = sAddr[k];
        if (a != 0xFFFFFFFFu) slots[a] = sPay[k];
    }
}

// 4-wide slot fetch, CACHED loads (round-8; nt measured -12us worse).
__device__ __forceinline__ void load4(const u64* __restrict__ sp, int j, int c,
                                      u64& v0, u64& v1, u64& v2, u64& v3) {
    v0 = v1 = v2 = v3 = 0;
    if (j + 3 < c) {
        ll2 q0 = *((const ll2*)(sp + j));
        ll2 q1 = *((const ll2*)(sp + j) + 1);
        v0 = (u64)q0.x; v1 = (u64)q0.y; v2 = (u64)q1.x; v3 = (u64)q1.y;
    } else if (j < c) {
        v0 = sp[j];
        if (j + 1 < c) v1 = sp[j + 1];
        if (j + 2 < c) v2 = sp[j + 2];
    }
}

// Per-bin: deg/count via packed (1<<20)|wq atomics (PREDICATED — counts must
// be exact for layer1's bias removal); dinv; y = fp16(x*dinv); rowCnt.
__global__ __launch_bounds__(AGG_THREADS, 4)
void k_deg_dinv(const u64* __restrict__ slots, const int* __restrict__ gCnt,
                const float4* __restrict__ x, float* __restrict__ dinv,
                h4* __restrict__ y, int* __restrict__ rowCnt, int N, int cap) {
    __shared__ unsigned degLds[NPB];
    const int b = blockIdx.x;
    for (int t = threadIdx.x; t < NPB; t += AGG_THREADS) degLds[t] = 0u;
    __syncthreads();
    const int c = min(gCnt[b], cap);
    const u64* sp = slots + (size_t)b * cap;
    const int CH = AGG_THREADS * 4;
    for (int base = 0; base < c; base += CH) {
        int j = base + (threadIdx.x << 2);
        u64 v0, v1, v2, v3;
        load4(sp, j, c, v0, v1, v2, v3);
        if (j < c)     atomicAdd(&degLds[((unsigned)v0) >> 23],
                                 (1u << 20) | (unsigned)(v0 >> 32));
        if (j + 1 < c) atomicAdd(&degLds[((unsigned)v1) >> 23],
                                 (1u << 20) | (unsigned)(v1 >> 32));
        if (j + 2 < c) atomicAdd(&degLds[((unsigned)v2) >> 23],
                                 (1u << 20) | (unsigned)(v2 >> 32));
        if (j + 3 < c) atomicAdd(&degLds[((unsigned)v3) >> 23],
                                 (1u << 20) | (unsigned)(v3 >> 32));
    }
    __syncthreads();
    for (int t = threadIdx.x; t < NPB; t += AGG_THREADS) {
        int n = (b << NPB_SHIFT) + t;
        if (n < N) {
            unsigned dc = degLds[t];
            float di = rsqrtf(1.0f + (float)(dc & 0xFFFFFu) * INV11);
            dinv[n] = di;
            rowCnt[n] = (int)(dc >> 20);
            float4 xv = x[n];
            h4 hv;
            hv.a = __floats2half2_rn(xv.x * di, xv.y * di);
            hv.b = __floats2half2_rn(xv.z * di, xv.w * di);
            y[n] = hv;
        }
    }
}

// Per-bin layer1: u64-packed LDS atomics (2/edge), biased fields; fused MLP.
__global__ __launch_bounds__(AGG_THREADS, 4)
void k_layer1(const u64* __restrict__ slots, const int* __restrict__ gCnt,
              const float* __restrict__ dinv, const h4* __restrict__ yh,
              const int* __restrict__ rowCnt, const float* __restrict__ W1,
              const float* __restrict__ b1, const float* __restrict__ W2,
              float* __restrict__ z, int N, int cap) {
    __shared__ u64 acc2[NPB][2];    // [n][0]=ch0|ch1, [n][1]=ch2|ch3 (biased)
    __shared__ float dLds[NPB];
    __shared__ float sW1[64], sb1[16], sW2[16];
    if (threadIdx.x < 64) sW1[threadIdx.x] = W1[threadIdx.x];
    if (threadIdx.x < 16) {
        sb1[threadIdx.x] = b1[threadIdx.x];
        sW2[threadIdx.x] = W2[threadIdx.x];
    }
    const int b = blockIdx.x;
    for (int t = threadIdx.x; t < NPB; t += AGG_THREADS) {
        acc2[t][0] = 0ULL; acc2[t][1] = 0ULL;
        int n = (b << NPB_SHIFT) + t;
        dLds[t] = (n < N) ? dinv[n] : 0.0f;
    }
    __syncthreads();
    const int c = min(gCnt[b], cap);
    const u64* sp = slots + (size_t)b * cap;
    const int CH = AGG_THREADS * 4;
    for (int base = 0; base < c; base += CH) {
        int j = base + (threadIdx.x << 2);
        u64 v0, v1, v2, v3;
        load4(sp, j, c, v0, v1, v2, v3);
        unsigned pk0 = (unsigned)v0, pk1 = (unsigned)v1,
                 pk2 = (unsigned)v2, pk3 = (unsigned)v3;
        // wq*y*2048 == (wq/2048)*y*2^22 -> q22 contribution
        float w0 = (float)(unsigned)(v0 >> 32) * 2048.0f;
        float w1 = (float)(unsigned)(v1 >> 32) * 2048.0f;
        float w2 = (float)(unsigned)(v2 >> 32) * 2048.0f;
        float w3 = (float)(unsigned)(v3 >> 32) * 2048.0f;
        // 4 independent gathers in flight (cached; y table is 4MB)
        h4 g0 = yh[pk0 & 0x7FFFFF];
        h4 g1 = yh[pk1 & 0x7FFFFF];
        h4 g2 = yh[pk2 & 0x7FFFFF];
        h4 g3 = yh[pk3 & 0x7FFFFF];
        float4 f0 = h4_to_f4(g0), f1 = h4_to_f4(g1),
               f2 = h4_to_f4(g2), f3 = h4_to_f4(g3);
        int d0 = pk0 >> 23, d1 = pk1 >> 23, d2 = pk2 >> 23, d3 = pk3 >> 23;
#define PACK2(wf, fa, fb) \
        (((u64)(unsigned)(__float2int_rn((wf) * (fb)) + (int)BIAS) << 32) | \
          (u64)(unsigned)(__float2int_rn((wf) * (fa)) + (int)BIAS))
        if (j < c) {
            atomicAdd(&acc2[d0][0], PACK2(w0, f0.x, f0.y));
            atomicAdd(&acc2[d0][1], PACK2(w0, f0.z, f0.w));
        }
        if (j + 1 < c) {
            atomicAdd(&acc2[d1][0], PACK2(w1, f1.x, f1.y));
            atomicAdd(&acc2[d1][1], PACK2(w1, f1.z, f1.w));
        }
        if (j + 2 < c) {
            atomicAdd(&acc2[d2][0], PACK2(w2, f2.x, f2.y));
            atomicAdd(&acc2[d2][1], PACK2(w2, f2.z, f2.w));
        }
        if (j + 3 < c) {
            atomicAdd(&acc2[d3][0], PACK2(w3, f3.x, f3.y));
            atomicAdd(&acc2[d3][1], PACK2(w3, f3.z, f3.w));
        }
#undef PACK2
    }
    __syncthreads();
    for (int t = threadIdx.x; t < NPB; t += AGG_THREADS) {
        int n = (b << NPB_SHIFT) + t;
        if (n >= N) continue;
        unsigned cb = (unsigned)rowCnt[n] * BIAS;
        u64 p01 = acc2[t][0], p23 = acc2[t][1];
        int a0 = (int)((unsigned)(p01 & 0xFFFFFFFFu) - cb);
        int a1 = (int)((unsigned)(p01 >> 32) - cb);
        int a2 = (int)((unsigned)(p23 & 0xFFFFFFFFu) - cb);
        int a3 = (int)((unsigned)(p23 >> 32) - cb);
        float di = dLds[t];
        float4 yv = h4_to_f4(yh[n]);
        float ax = di * (yv.x + (float)a0 * A1_INV);
        float ay = di * (yv.y + (float)a1 * A1_INV);
        float az = di * (yv.z + (float)a2 * A1_INV);
        float aw = di * (yv.w + (float)a3 * A1_INV);
        float sacc = 0.0f;
#pragma unroll
        for (int k = 0; k < 16; ++k) {
            float h = ax * sW1[k] + ay * sW1[16 + k] + az * sW1[32 + k]
                    + aw * sW1[48 + k] + sb1[k];
            sacc += fmaxf(h, 0.0f) * sW2[k];
        }
        z[n] = sacc * di;
    }
}

// Per-bin layer2: out[n] = di*(z[n] + sum w*z[s]) + b2. 1 atomic/edge;
// sentinel wq=0 contributes 0 -> unconditional adds are safe here.
__global__ __launch_bounds__(AGG_THREADS, 4)
void k_layer2(const u64* __restrict__ slots, const int* __restrict__ gCnt,
              const float* __restrict__ dinv, const float* __restrict__ z,
              const float* __restrict__ b2, float* __restrict__ out,
              int N, int cap) {
    __shared__ int accs[NPB];
    __shared__ float dLds[NPB];
    const int b = blockIdx.x;
    for (int t = threadIdx.x; t < NPB; t += AGG_THREADS) {
        accs[t] = 0;
        int n = (b << NPB_SHIFT) + t;
        dLds[t] = (n < N) ? dinv[n] : 0.0f;
    }
    __syncthreads();
    const int c = min(gCnt[b], cap);
    const u64* sp = slots + (size_t)b * cap;
    const int CH = AGG_THREADS * 4;
    for (int base = 0; base < c; base += CH) {
        int j = base + (threadIdx.x << 2);
        u64 v0, v1, v2, v3;
        load4(sp, j, c, v0, v1, v2, v3);
        unsigned pk0 = (unsigned)v0, pk1 = (unsigned)v1,
                 pk2 = (unsigned)v2, pk3 = (unsigned)v3;
        float z0 = z[pk0 & 0x7FFFFF];
        float z1 = z[pk1 & 0x7FFFFF];
        float z2 = z[pk2 & 0x7FFFFF];
        float z3 = z[pk3 & 0x7FFFFF];
        // w*z*2^20 = wq*z*512
        atomicAdd(&accs[pk0 >> 23],
                  __float2int_rn((float)(unsigned)(v0 >> 32) * z0 * 512.0f));
        atomicAdd(&accs[pk1 >> 23],
                  __float2int_rn((float)(unsigned)(v1 >> 32) * z1 * 512.0f));
        atomicAdd(&accs[pk2 >> 23],
                  __float2int_rn((float)(unsigned)(v2 >> 32) * z2 * 512.0f));
        atomicAdd(&accs[pk3 >> 23],
                  __float2int_rn((float)(unsigned)(v3 >> 32) * z3 * 512.0f));
    }
    __syncthreads();
    const float bb2 = b2[0];
    for (int t = threadIdx.x; t < NPB; t += AGG_THREADS) {
        int n = (b << NPB_SHIFT) + t;
        if (n < N) out[n] = dLds[t] * (z[n] + (float)accs[t] * A2_INV) + bb2;
    }
}

// ------------------------- fallback (round-1) path -------------------------
__global__ __launch_bounds__(256)
void k_init(float* __restrict__ deg, int N) {
    int i = blockIdx.x * blockDim.x + threadIdx.x;
    if (i < N) deg[i] = 1.0f;
}

__global__ __launch_bounds__(256)
void k_deg(const void* __restrict__ idx, const float* __restrict__ ew,
           float* __restrict__ deg, int E, const int* __restrict__ flag) {
    const bool is64 = (*flag != 0);
    const int stride = gridDim.x * blockDim.x;
    for (int e = blockIdx.x * blockDim.x + threadIdx.x; e < E; e += stride) {
        int d = is64 ? (int)((const long long*)idx)[(long long)E + e]
                     : ((const int*)idx)[E + e];
        atomicAdd(deg + d, ew[e]);
    }
}

__global__ __launch_bounds__(256)
void k_dinv_accx(float* __restrict__ deg_dinv, const float4* __restrict__ x,
                 float4* __restrict__ accx, int N) {
    int n = blockIdx.x * blockDim.x + threadIdx.x;
    if (n >= N) return;
    float dg = deg_dinv[n];
    float di = (dg > 0.0f) ? rsqrtf(dg) : 0.0f;
    deg_dinv[n] = di;
    float sn = di * di;
    float4 xv = x[n];
    accx[n] = make_float4(xv.x * sn, xv.y * sn, xv.z * sn, xv.w * sn);
}

__global__ __launch_bounds__(256)
void k_scatter1(const void* __restrict__ idx, const float* __restrict__ ew,
                const float* __restrict__ dinv, const float4* __restrict__ x,
                float* __restrict__ accx, int E, const int* __restrict__ flag) {
    const bool is64 = (*flag != 0);
    const int stride = gridDim.x * blockDim.x;
    for (int e = blockIdx.x * blockDim.x + threadIdx.x; e < E; e += stride) {
        int s, d;
        if (is64) {
            const long long* p = (const long long*)idx;
            s = (int)p[e]; d = (int)p[(long long)E + e];
        } else {
            const int* p = (const int*)idx;
            s = p[e]; d = p[E + e];
        }
        float nm = dinv[s] * ew[e] * dinv[d];
        float4 xv = x[s];
        float* dp = accx + (size_t)d * 4;
        atomicAdd(dp + 0, nm * xv.x);
        atomicAdd(dp + 1, nm * xv.y);
        atomicAdd(dp + 2, nm * xv.z);
        atomicAdd(dp + 3, nm * xv.w);
    }
}

__global__ __launch_bounds__(256)
void k_node2(const float4* __restrict__ accx, const float* __restrict__ dinv,
             const float* __restrict__ W1, const float* __restrict__ b1,
             const float* __restrict__ W2, const float* __restrict__ b2,
             float* __restrict__ s2, float* __restrict__ out, int N) {
    __shared__ float sW1[64], sb1[16], sW2[16];
    if (threadIdx.x < 64) sW1[threadIdx.x] = W1[threadIdx.x];
    if (threadIdx.x < 16) {
        sb1[threadIdx.x] = b1[threadIdx.x];
        sW2[threadIdx.x] = W2[threadIdx.x];
    }
    __syncthreads();
    int n = blockIdx.x * blockDim.x + threadIdx.x;
    if (n >= N) return;
    float bb2 = b2[0];
    float4 a = accx[n];
    float acc = 0.0f;
#pragma unroll
    for (int k = 0; k < 16; ++k) {
        float h = a.x * sW1[k] + a.y * sW1[16 + k] + a.z * sW1[32 + k]
                + a.w * sW1[48 + k] + sb1[k];
        acc += fmaxf(h, 0.0f) * sW2[k];
    }
    s2[n] = acc;
    float di = dinv[n];
    out[n] = acc * di * di + bb2;
}

__global__ __launch_bounds__(256)
void k_scatter2(const void* __restrict__ idx, const float* __restrict__ ew,
                const float* __restrict__ dinv, const float* __restrict__ s2,
                float* __restrict__ out, int E, const int* __restrict__ flag) {
    const bool is64 = (*flag != 0);
    const int stride = gridDim.x * blockDim.x;
    for (int e = blockIdx.x * blockDim.x + threadIdx.x; e < E; e += stride) {
        int s, d;
        if (is64) {
            const long long* p = (const long long*)idx;
            s = (int)p[e]; d = (int)p[(long long)E + e];
        } else {
            const int* p = (const int*)idx;
            s = p[e]; d = p[E + e];
        }
        float nm = dinv[s] * ew[e] * dinv[d];
        atomicAdd(out + d, nm * s2[s]);
    }
}

// ---------------------------------------------------------------------------
extern "C" void kernel_launch(void* const* d_in, const int* in_sizes, int n_in,
                              void* d_out, int out_size, void* d_ws, size_t ws_size,
                              hipStream_t stream) {
    const float* x   = (const float*)d_in[0];
    const void*  eix = d_in[1];
    const float* ew  = (const float*)d_in[2];
    const float* W1  = (const float*)d_in[3];
    const float* b1  = (const float*)d_in[4];
    const float* W2  = (const float*)d_in[5];
    const float* b2  = (const float*)d_in[6];
    float* out = (float*)d_out;

    const int N = in_sizes[0] / 4;   // x is [N,4]
    const int E = in_sizes[2];       // edge_weight is [E]

    const int B = (N + NPB - 1) >> NPB_SHIFT;
    int cap = (E / B + 2048 + 3) & ~3;   // mean + ~23 sigma, multiple of 4
    const int nCheck = (E < 65536) ? E : 65536;

    // ws: y h4[N] | slots u64[B*cap] | gCnt[B] | rowCnt[N] | dinv[N] | z[N] | flag
    size_t need = (size_t)N * 8 + (size_t)B * cap * 8
                + (size_t)B * 4 + (size_t)N * 12 + 256;

    bool addr32ok = ((long long)B * cap) < 0xFFFFFFFFLL;

    if (B <= MAX_BINS && N < (1 << 23) && ws_size >= need && addr32ok) {
        h4* y = (h4*)d_ws;
        u64* slots = (u64*)(y + N);
        int*   gCnt = (int*)(slots + (size_t)B * cap);
        int*   rowCnt = gCnt + B;
        float* dinv = (float*)(rowCnt + N);
        float* z    = dinv + N;
        int*   flag = (int*)(z + N);

        const int part_blocks = (E + PART_CHUNK - 1) / PART_CHUNK;

        k_zero<<<(B + 255) / 256, 256, 0, stream>>>(gCnt, B);
        k_detect<<<1, 1024, 0, stream>>>((const unsigned int*)eix, nCheck, flag);
        k_partition<<<part_blocks, PART_THREADS, 0, stream>>>(eix, ew, gCnt, slots,
                                                              E, B, cap, flag);
        k_deg_dinv<<<B, AGG_THREADS, 0, stream>>>(slots, gCnt, (const float4*)x,
                                                  dinv, y, rowCnt, N, cap);
        k_layer1<<<B, AGG_THREADS, 0, stream>>>(slots, gCnt, dinv, y, rowCnt,
                                                W1, b1, W2, z, N, cap);
        k_layer2<<<B, AGG_THREADS, 0, stream>>>(slots, gCnt, dinv, z, b2, out, N, cap);
    } else {
        // fallback: direct atomic scatter (round-1)
        const int nb_n = (N + 255) / 256;
        const int nb_e = min((E + 255) / 256, 16384);
        float* deg  = (float*)d_ws;
        float* accx = deg + N;
        float* s2   = accx + (size_t)4 * N;
        int*   flag = (int*)(s2 + N);

        k_init<<<nb_n, 256, 0, stream>>>(deg, N);
        k_detect<<<1, 1024, 0, stream>>>((const unsigned int*)eix, nCheck, flag);
        k_deg<<<nb_e, 256, 0, stream>>>(eix, ew, deg, E, flag);
        k_dinv_accx<<<nb_n, 256, 0, stream>>>(deg, (const float4*)x, (float4*)accx, N);
        k_scatter1<<<nb_e, 256, 0, stream>>>(eix, ew, deg, (const float4*)x, accx, E, flag);
        k_node2<<<nb_n, 256, 0, stream>>>((const float4*)accx, deg, W1, b1, W2, b2, s2, out, N);
        k_scatter2<<<nb_e, 256, 0, stream>>>(eix, ew, deg, s2, out, E, flag);
    }
}

// Round 18
// 195.648 us; speedup vs baseline: 1.6377x; 1.1612x over previous
//
#include <hip/hip_runtime.h>
#include <hip/hip_fp16.h>

// ---------------------------------------------------------------------------
// CrowdGNN: 2-layer GCN, N=500k nodes, E=8M edges (+ implicit self loops).
// Round-18 = round-17 champion (227.2us) + partition chunk 4096->8192:
//   - partition is latency/phase-bound (FETCH 47MB: L3-resident inputs;
//     1.84TB/s, VALU 12%): halve block count & barriers, double bin-run
//     length (32B->64B) to cut write sector amplification (106->~90MB).
//     MLP preserved: 16 waves x 16 loads in flight == 32 x 8.
//   - k_zero + k_detect merged into k_prep (one launch fewer).
// Agg side unchanged: deg (packed count|wsum u32 atomics, predicated),
// layer1 (u64-packed 2-atomic/edge, BIAS=2^25 fields, rowCnt bias removal),
// layer2 (1 int atomic/edge). Fixed-point wq q11, y fp16, acc q22/q20.
// ---------------------------------------------------------------------------

typedef unsigned long long u64;
typedef long long ll2 __attribute__((ext_vector_type(2)));

#define NPB_SHIFT 9
#define NPB 512
#define MAX_BINS 1024
#define PART_THREADS 1024
#define PART_EPT 8
#define PART_CHUNK (PART_THREADS * PART_EPT)   // 8192 edges per block
#define AGG_THREADS 512

#define Q11      2048.0f
#define INV11    (1.0f / 2048.0f)
#define A1_INV   (1.0f / 4194304.0f)   // q22
#define A2_INV   (1.0f / 1048576.0f)   // q20
#define BIAS     (1u << 25)            // per-edge field bias, > max|c|=2^24.4

struct h4 { __half2 a, b; };

__device__ __forceinline__ float4 h4_to_f4(h4 v) {
    float2 lo = __half22float2(v.a);
    float2 hi = __half22float2(v.b);
    return make_float4(lo.x, lo.y, hi.x, hi.y);
}

// One launch: zero gCnt (all threads) + int64/int32 detect (block 0).
__global__ __launch_bounds__(1024)
void k_prep(const unsigned int* __restrict__ idx_words, int nCheck, int* flag,
            int* __restrict__ gCnt, int B, int nBlocks) {
    int gid = blockIdx.x * 1024 + threadIdx.x;
    for (int i = gid; i < B; i += nBlocks * 1024) gCnt[i] = 0;
    if (blockIdx.x == 0) {
        __shared__ int cnt;
        if (threadIdx.x == 0) cnt = 0;
        __syncthreads();
        int local = 0;
        for (int i = threadIdx.x; i < nCheck; i += 1024)
            local += (idx_words[2 * i + 1] != 0u) ? 1 : 0;
        if (local) atomicAdd(&cnt, local);
        __syncthreads();
        if (threadIdx.x == 0) *flag = (cnt < 8) ? 1 : 0;
    }
}

// Bin-sorted-staging partition; payload carries wq q11. 8192 edges/block.
__global__ __launch_bounds__(PART_THREADS)
void k_partition(const void* __restrict__ idx, const float* __restrict__ ew,
                 int* __restrict__ gCnt, u64* __restrict__ slots,
                 int E, int B, int cap, const int* __restrict__ flag) {
    __shared__ int lcnt[MAX_BINS];
    __shared__ int lbase[MAX_BINS];
    __shared__ int lstart[MAX_BINS];
    __shared__ u64 sPay[PART_CHUNK];
    __shared__ unsigned sAddr[PART_CHUNK];
    __shared__ int waveSum[PART_THREADS / 64];

    const bool is64 = (*flag != 0);
    const int tid = threadIdx.x;
    for (int i = tid; i < MAX_BINS; i += PART_THREADS) lcnt[i] = 0;
    __syncthreads();

    const int base_e = blockIdx.x * PART_CHUNK;
    const int nValid = min(PART_CHUNK, E - base_e);

    u64 pay[PART_EPT];
    int bin_[PART_EPT], r_[PART_EPT];
#pragma unroll
    for (int i = 0; i < PART_EPT; ++i) {
        int e = base_e + i * PART_THREADS + tid;
        bin_[i] = -1;
        if (e < E) {
            int s, d;
            if (is64) {
                const long long* p = (const long long*)idx;
                s = (int)__builtin_nontemporal_load(p + e);
                d = (int)__builtin_nontemporal_load(p + (long long)E + e);
            } else {
                const int* p = (const int*)idx;
                s = __builtin_nontemporal_load(p + e);
                d = __builtin_nontemporal_load(p + E + e);
            }
            float w = __builtin_nontemporal_load(ew + e);
            int bin = d >> NPB_SHIFT;
            unsigned wq = min((unsigned)__float2int_rn(w * Q11), 2047u);
            unsigned pk = ((unsigned)(d & (NPB - 1)) << 23) | (unsigned)s;
            pay[i] = ((u64)wq << 32) | pk;
            bin_[i] = bin;
            r_[i] = atomicAdd(&lcnt[bin], 1);
        }
    }
    __syncthreads();

    {
        const int lane = tid & 63, wid = tid >> 6;
        const int v = lcnt[tid];
        int inc = v;
#pragma unroll
        for (int off = 1; off < 64; off <<= 1) {
            int t = __shfl_up(inc, off, 64);
            if (lane >= off) inc += t;
        }
        if (lane == 63) waveSum[wid] = inc;
        __syncthreads();
        if (wid == 0) {
            const int NW = PART_THREADS / 64;
            int wv = (lane < NW) ? waveSum[lane] : 0;
            int winc = wv;
#pragma unroll
            for (int off = 1; off < NW; off <<= 1) {
                int t = __shfl_up(winc, off, 64);
                if (lane >= off) winc += t;
            }
            if (lane < NW) waveSum[lane] = winc - wv;
        }
        __syncthreads();
        lstart[tid] = inc - v + waveSum[wid];
        lbase[tid] = (v > 0 && tid < B) ? atomicAdd(&gCnt[tid], v) : 0;
    }
    __syncthreads();

#pragma unroll
    for (int i = 0; i < PART_EPT; ++i) {
        if (bin_[i] >= 0) {
            int si = lstart[bin_[i]] + r_[i];
            long long pos = (long long)lbase[bin_[i]] + r_[i];
            sPay[si] = pay[i];
            sAddr[si] = (pos < cap)
                      ? (unsigned)((long long)bin_[i] * cap + pos)
                      : 0xFFFFFFFFu;
        }
    }
    __syncthreads();

    for (int k = tid; k < nValid; k += PART_THREADS) {
        unsigned a = sAddr[k];
        if (a != 0xFFFFFFFFu) slots[a] = sPay[k];
    }
}

// 4-wide slot fetch, CACHED loads (nt measured -12us worse on this stream).
__device__ __forceinline__ void load4(const u64* __restrict__ sp, int j, int c,
                                      u64& v0, u64& v1, u64& v2, u64& v3) {
    v0 = v1 = v2 = v3 = 0;
    if (j + 3 < c) {
        ll2 q0 = *((const ll2*)(sp + j));
        ll2 q1 = *((const ll2*)(sp + j) + 1);
        v0 = (u64)q0.x; v1 = (u64)q0.y; v2 = (u64)q1.x; v3 = (u64)q1.y;
    } else if (j < c) {
        v0 = sp[j];
        if (j + 1 < c) v1 = sp[j + 1];
        if (j + 2 < c) v2 = sp[j + 2];
    }
}

// Per-bin: deg/count via packed (1<<20)|wq atomics (PREDICATED — counts must
// be exact for layer1's bias removal); dinv; y = fp16(x*dinv); rowCnt.
__global__ __launch_bounds__(AGG_THREADS, 4)
void k_deg_dinv(const u64* __restrict__ slots, const int* __restrict__ gCnt,
                const float4* __restrict__ x, float* __restrict__ dinv,
                h4* __restrict__ y, int* __restrict__ rowCnt, int N, int cap) {
    __shared__ unsigned degLds[NPB];
    const int b = blockIdx.x;
    for (int t = threadIdx.x; t < NPB; t += AGG_THREADS) degLds[t] = 0u;
    __syncthreads();
    const int c = min(gCnt[b], cap);
    const u64* sp = slots + (size_t)b * cap;
    const int CH = AGG_THREADS * 4;
    for (int base = 0; base < c; base += CH) {
        int j = base + (threadIdx.x << 2);
        u64 v0, v1, v2, v3;
        load4(sp, j, c, v0, v1, v2, v3);
        if (j < c)     atomicAdd(&degLds[((unsigned)v0) >> 23],
                                 (1u << 20) | (unsigned)(v0 >> 32));
        if (j + 1 < c) atomicAdd(&degLds[((unsigned)v1) >> 23],
                                 (1u << 20) | (unsigned)(v1 >> 32));
        if (j + 2 < c) atomicAdd(&degLds[((unsigned)v2) >> 23],
                                 (1u << 20) | (unsigned)(v2 >> 32));
        if (j + 3 < c) atomicAdd(&degLds[((unsigned)v3) >> 23],
                                 (1u << 20) | (unsigned)(v3 >> 32));
    }
    __syncthreads();
    for (int t = threadIdx.x; t < NPB; t += AGG_THREADS) {
        int n = (b << NPB_SHIFT) + t;
        if (n < N) {
            unsigned dc = degLds[t];
            float di = rsqrtf(1.0f + (float)(dc & 0xFFFFFu) * INV11);
            dinv[n] = di;
            rowCnt[n] = (int)(dc >> 20);
            float4 xv = x[n];
            h4 hv;
            hv.a = __floats2half2_rn(xv.x * di, xv.y * di);
            hv.b = __floats2half2_rn(xv.z * di, xv.w * di);
            y[n] = hv;
        }
    }
}

// Per-bin layer1: u64-packed LDS atomics (2/edge), biased fields; fused MLP.
__global__ __launch_bounds__(AGG_THREADS, 4)
void k_layer1(const u64* __restrict__ slots, const int* __restrict__ gCnt,
              const float* __restrict__ dinv, const h4* __restrict__ yh,
              const int* __restrict__ rowCnt, const float* __restrict__ W1,
              const float* __restrict__ b1, const float* __restrict__ W2,
              float* __restrict__ z, int N, int cap) {
    __shared__ u64 acc2[NPB][2];    // [n][0]=ch0|ch1, [n][1]=ch2|ch3 (biased)
    __shared__ float dLds[NPB];
    __shared__ float sW1[64], sb1[16], sW2[16];
    if (threadIdx.x < 64) sW1[threadIdx.x] = W1[threadIdx.x];
    if (threadIdx.x < 16) {
        sb1[threadIdx.x] = b1[threadIdx.x];
        sW2[threadIdx.x] = W2[threadIdx.x];
    }
    const int b = blockIdx.x;
    for (int t = threadIdx.x; t < NPB; t += AGG_THREADS) {
        acc2[t][0] = 0ULL; acc2[t][1] = 0ULL;
        int n = (b << NPB_SHIFT) + t;
        dLds[t] = (n < N) ? dinv[n] : 0.0f;
    }
    __syncthreads();
    const int c = min(gCnt[b], cap);
    const u64* sp = slots + (size_t)b * cap;
    const int CH = AGG_THREADS * 4;
    for (int base = 0; base < c; base += CH) {
        int j = base + (threadIdx.x << 2);
        u64 v0, v1, v2, v3;
        load4(sp, j, c, v0, v1, v2, v3);
        unsigned pk0 = (unsigned)v0, pk1 = (unsigned)v1,
                 pk2 = (unsigned)v2, pk3 = (unsigned)v3;
        // wq*y*2048 == (wq/2048)*y*2^22 -> q22 contribution
        float w0 = (float)(unsigned)(v0 >> 32) * 2048.0f;
        float w1 = (float)(unsigned)(v1 >> 32) * 2048.0f;
        float w2 = (float)(unsigned)(v2 >> 32) * 2048.0f;
        float w3 = (float)(unsigned)(v3 >> 32) * 2048.0f;
        // 4 independent gathers in flight (cached; y table is 4MB)
        h4 g0 = yh[pk0 & 0x7FFFFF];
        h4 g1 = yh[pk1 & 0x7FFFFF];
        h4 g2 = yh[pk2 & 0x7FFFFF];
        h4 g3 = yh[pk3 & 0x7FFFFF];
        float4 f0 = h4_to_f4(g0), f1 = h4_to_f4(g1),
               f2 = h4_to_f4(g2), f3 = h4_to_f4(g3);
        int d0 = pk0 >> 23, d1 = pk1 >> 23, d2 = pk2 >> 23, d3 = pk3 >> 23;
#define PACK2(wf, fa, fb) \
        (((u64)(unsigned)(__float2int_rn((wf) * (fb)) + (int)BIAS) << 32) | \
          (u64)(unsigned)(__float2int_rn((wf) * (fa)) + (int)BIAS))
        if (j < c) {
            atomicAdd(&acc2[d0][0], PACK2(w0, f0.x, f0.y));
            atomicAdd(&acc2[d0][1], PACK2(w0, f0.z, f0.w));
        }
        if (j + 1 < c) {
            atomicAdd(&acc2[d1][0], PACK2(w1, f1.x, f1.y));
            atomicAdd(&acc2[d1][1], PACK2(w1, f1.z, f1.w));
        }
        if (j + 2 < c) {
            atomicAdd(&acc2[d2][0], PACK2(w2, f2.x, f2.y));
            atomicAdd(&acc2[d2][1], PACK2(w2, f2.z, f2.w));
        }
        if (j + 3 < c) {
            atomicAdd(&acc2[d3][0], PACK2(w3, f3.x, f3.y));
            atomicAdd(&acc2[d3][1], PACK2(w3, f3.z, f3.w));
        }
#undef PACK2
    }
    __syncthreads();
    for (int t = threadIdx.x; t < NPB; t += AGG_THREADS) {
        int n = (b << NPB_SHIFT) + t;
        if (n >= N) continue;
        unsigned cb = (unsigned)rowCnt[n] * BIAS;
        u64 p01 = acc2[t][0], p23 = acc2[t][1];
        int a0 = (int)((unsigned)(p01 & 0xFFFFFFFFu) - cb);
        int a1 = (int)((unsigned)(p01 >> 32) - cb);
        int a2 = (int)((unsigned)(p23 & 0xFFFFFFFFu) - cb);
        int a3 = (int)((unsigned)(p23 >> 32) - cb);
        float di = dLds[t];
        float4 yv = h4_to_f4(yh[n]);
        float ax = di * (yv.x + (float)a0 * A1_INV);
        float ay = di * (yv.y + (float)a1 * A1_INV);
        float az = di * (yv.z + (float)a2 * A1_INV);
        float aw = di * (yv.w + (float)a3 * A1_INV);
        float sacc = 0.0f;
#pragma unroll
        for (int k = 0; k < 16; ++k) {
            float h = ax * sW1[k] + ay * sW1[16 + k] + az * sW1[32 + k]
                    + aw * sW1[48 + k] + sb1[k];
            sacc += fmaxf(h, 0.0f) * sW2[k];
        }
        z[n] = sacc * di;
    }
}

// Per-bin layer2: out[n] = di*(z[n] + sum w*z[s]) + b2. 1 atomic/edge;
// sentinel wq=0 contributes 0 -> unconditional adds are safe here.
__global__ __launch_bounds__(AGG_THREADS, 4)
void k_layer2(const u64* __restrict__ slots, const int* __restrict__ gCnt,
              const float* __restrict__ dinv, const float* __restrict__ z,
              const float* __restrict__ b2, float* __restrict__ out,
              int N, int cap) {
    __shared__ int accs[NPB];
    __shared__ float dLds[NPB];
    const int b = blockIdx.x;
    for (int t = threadIdx.x; t < NPB; t += AGG_THREADS) {
        accs[t] = 0;
        int n = (b << NPB_SHIFT) + t;
        dLds[t] = (n < N) ? dinv[n] : 0.0f;
    }
    __syncthreads();
    const int c = min(gCnt[b], cap);
    const u64* sp = slots + (size_t)b * cap;
    const int CH = AGG_THREADS * 4;
    for (int base = 0; base < c; base += CH) {
        int j = base + (threadIdx.x << 2);
        u64 v0, v1, v2, v3;
        load4(sp, j, c, v0, v1, v2, v3);
        unsigned pk0 = (unsigned)v0, pk1 = (unsigned)v1,
                 pk2 = (unsigned)v2, pk3 = (unsigned)v3;
        float z0 = z[pk0 & 0x7FFFFF];
        float z1 = z[pk1 & 0x7FFFFF];
        float z2 = z[pk2 & 0x7FFFFF];
        float z3 = z[pk3 & 0x7FFFFF];
        // w*z*2^20 = wq*z*512
        atomicAdd(&accs[pk0 >> 23],
                  __float2int_rn((float)(unsigned)(v0 >> 32) * z0 * 512.0f));
        atomicAdd(&accs[pk1 >> 23],
                  __float2int_rn((float)(unsigned)(v1 >> 32) * z1 * 512.0f));
        atomicAdd(&accs[pk2 >> 23],
                  __float2int_rn((float)(unsigned)(v2 >> 32) * z2 * 512.0f));
        atomicAdd(&accs[pk3 >> 23],
                  __float2int_rn((float)(unsigned)(v3 >> 32) * z3 * 512.0f));
    }
    __syncthreads();
    const float bb2 = b2[0];
    for (int t = threadIdx.x; t < NPB; t += AGG_THREADS) {
        int n = (b << NPB_SHIFT) + t;
        if (n < N) out[n] = dLds[t] * (z[n] + (float)accs[t] * A2_INV) + bb2;
    }
}

// ------------------------- fallback (round-1) path -------------------------
__global__ __launch_bounds__(1024)
void k_detect(const unsigned int* __restrict__ idx_words, int nCheck, int* flag) {
    __shared__ int cnt;
    if (threadIdx.x == 0) cnt = 0;
    __syncthreads();
    int local = 0;
    for (int i = threadIdx.x; i < nCheck; i += blockDim.x)
        local += (idx_words[2 * i + 1] != 0u) ? 1 : 0;
    if (local) atomicAdd(&cnt, local);
    __syncthreads();
    if (threadIdx.x == 0) *flag = (cnt < 8) ? 1 : 0;
}

__global__ __launch_bounds__(256)
void k_init(float* __restrict__ deg, int N) {
    int i = blockIdx.x * blockDim.x + threadIdx.x;
    if (i < N) deg[i] = 1.0f;
}

__global__ __launch_bounds__(256)
void k_deg(const void* __restrict__ idx, const float* __restrict__ ew,
           float* __restrict__ deg, int E, const int* __restrict__ flag) {
    const bool is64 = (*flag != 0);
    const int stride = gridDim.x * blockDim.x;
    for (int e = blockIdx.x * blockDim.x + threadIdx.x; e < E; e += stride) {
        int d = is64 ? (int)((const long long*)idx)[(long long)E + e]
                     : ((const int*)idx)[E + e];
        atomicAdd(deg + d, ew[e]);
    }
}

__global__ __launch_bounds__(256)
void k_dinv_accx(float* __restrict__ deg_dinv, const float4* __restrict__ x,
                 float4* __restrict__ accx, int N) {
    int n = blockIdx.x * blockDim.x + threadIdx.x;
    if (n >= N) return;
    float dg = deg_dinv[n];
    float di = (dg > 0.0f) ? rsqrtf(dg) : 0.0f;
    deg_dinv[n] = di;
    float sn = di * di;
    float4 xv = x[n];
    accx[n] = make_float4(xv.x * sn, xv.y * sn, xv.z * sn, xv.w * sn);
}

__global__ __launch_bounds__(256)
void k_scatter1(const void* __restrict__ idx, const float* __restrict__ ew,
                const float* __restrict__ dinv, const float4* __restrict__ x,
                float* __restrict__ accx, int E, const int* __restrict__ flag) {
    const bool is64 = (*flag != 0);
    const int stride = gridDim.x * blockDim.x;
    for (int e = blockIdx.x * blockDim.x + threadIdx.x; e < E; e += stride) {
        int s, d;
        if (is64) {
            const long long* p = (const long long*)idx;
            s = (int)p[e]; d = (int)p[(long long)E + e];
        } else {
            const int* p = (const int*)idx;
            s = p[e]; d = p[E + e];
        }
        float nm = dinv[s] * ew[e] * dinv[d];
        float4 xv = x[s];
        float* dp = accx + (size_t)d * 4;
        atomicAdd(dp + 0, nm * xv.x);
        atomicAdd(dp + 1, nm * xv.y);
        atomicAdd(dp + 2, nm * xv.z);
        atomicAdd(dp + 3, nm * xv.w);
    }
}

__global__ __launch_bounds__(256)
void k_node2(const float4* __restrict__ accx, const float* __restrict__ dinv,
             const float* __restrict__ W1, const float* __restrict__ b1,
             const float* __restrict__ W2, const float* __restrict__ b2,
             float* __restrict__ s2, float* __restrict__ out, int N) {
    __shared__ float sW1[64], sb1[16], sW2[16];
    if (threadIdx.x < 64) sW1[threadIdx.x] = W1[threadIdx.x];
    if (threadIdx.x < 16) {
        sb1[threadIdx.x] = b1[threadIdx.x];
        sW2[threadIdx.x] = W2[threadIdx.x];
    }
    __syncthreads();
    int n = blockIdx.x * blockDim.x + threadIdx.x;
    if (n >= N) return;
    float bb2 = b2[0];
    float4 a = accx[n];
    float acc = 0.0f;
#pragma unroll
    for (int k = 0; k < 16; ++k) {
        float h = a.x * sW1[k] + a.y * sW1[16 + k] + a.z * sW1[32 + k]
                + a.w * sW1[48 + k] + sb1[k];
        acc += fmaxf(h, 0.0f) * sW2[k];
    }
    s2[n] = acc;
    float di = dinv[n];
    out[n] = acc * di * di + bb2;
}

__global__ __launch_bounds__(256)
void k_scatter2(const void* __restrict__ idx, const float* __restrict__ ew,
                const float* __restrict__ dinv, const float* __restrict__ s2,
                float* __restrict__ out, int E, const int* __restrict__ flag) {
    const bool is64 = (*flag != 0);
    const int stride = gridDim.x * blockDim.x;
    for (int e = blockIdx.x * blockDim.x + threadIdx.x; e < E; e += stride) {
        int s, d;
        if (is64) {
            const long long* p = (const long long*)idx;
            s = (int)p[e]; d = (int)p[(long long)E + e];
        } else {
            const int* p = (const int*)idx;
            s = p[e]; d = p[E + e];
        }
        float nm = dinv[s] * ew[e] * dinv[d];
        atomicAdd(out + d, nm * s2[s]);
    }
}

// ---------------------------------------------------------------------------
extern "C" void kernel_launch(void* const* d_in, const int* in_sizes, int n_in,
                              void* d_out, int out_size, void* d_ws, size_t ws_size,
                              hipStream_t stream) {
    const float* x   = (const float*)d_in[0];
    const void*  eix = d_in[1];
    const float* ew  = (const float*)d_in[2];
    const float* W1  = (const float*)d_in[3];
    const float* b1  = (const float*)d_in[4];
    const float* W2  = (const float*)d_in[5];
    const float* b2  = (const float*)d_in[6];
    float* out = (float*)d_out;

    const int N = in_sizes[0] / 4;   // x is [N,4]
    const int E = in_sizes[2];       // edge_weight is [E]

    const int B = (N + NPB - 1) >> NPB_SHIFT;
    int cap = (E / B + 2048 + 3) & ~3;   // mean + ~23 sigma, multiple of 4
    const int nCheck = (E < 65536) ? E : 65536;

    // ws: y h4[N] | slots u64[B*cap] | gCnt[B] | rowCnt[N] | dinv[N] | z[N] | flag
    size_t need = (size_t)N * 8 + (size_t)B * cap * 8
                + (size_t)B * 4 + (size_t)N * 12 + 256;

    bool addr32ok = ((long long)B * cap) < 0xFFFFFFFFLL;

    if (B <= MAX_BINS && N < (1 << 23) && ws_size >= need && addr32ok) {
        h4* y = (h4*)d_ws;
        u64* slots = (u64*)(y + N);
        int*   gCnt = (int*)(slots + (size_t)B * cap);
        int*   rowCnt = gCnt + B;
        float* dinv = (float*)(rowCnt + N);
        float* z    = dinv + N;
        int*   flag = (int*)(z + N);

        const int part_blocks = (E + PART_CHUNK - 1) / PART_CHUNK;

        k_prep<<<2, 1024, 0, stream>>>((const unsigned int*)eix, nCheck, flag,
                                       gCnt, B, 2);
        k_partition<<<part_blocks, PART_THREADS, 0, stream>>>(eix, ew, gCnt, slots,
                                                              E, B, cap, flag);
        k_deg_dinv<<<B, AGG_THREADS, 0, stream>>>(slots, gCnt, (const float4*)x,
                                                  dinv, y, rowCnt, N, cap);
        k_layer1<<<B, AGG_THREADS, 0, stream>>>(slots, gCnt, dinv, y, rowCnt,
                                                W1, b1, W2, z, N, cap);
        k_layer2<<<B, AGG_THREADS, 0, stream>>>(slots, gCnt, dinv, z, b2, out, N, cap);
    } else {
        // fallback: direct atomic scatter (round-1)
        const int nb_n = (N + 255) / 256;
        const int nb_e = min((E + 255) / 256, 16384);
        float* deg  = (float*)d_ws;
        float* accx = deg + N;
        float* s2   = accx + (size_t)4 * N;
        int*   flag = (int*)(s2 + N);

        k_init<<<nb_n, 256, 0, stream>>>(deg, N);
        k_detect<<<1, 1024, 0, stream>>>((const unsigned int*)eix, nCheck, flag);
        k_deg<<<nb_e, 256, 0, stream>>>(eix, ew, deg, E, flag);
        k_dinv_accx<<<nb_n, 256, 0, stream>>>(deg, (const float4*)x, (float4*)accx, N);
        k_scatter1<<<nb_e, 256, 0, stream>>>(eix, ew, deg, (const float4*)x, accx, E, flag);
        k_node2<<<nb_n, 256, 0, stream>>>((const float4*)accx, deg, W1, b1, W2, b2, s2, out, N);
        k_scatter2<<<nb_e, 256, 0, stream>>>(eix, ew, deg, s2, out, E, flag);
    }
}

// Round 19
// 180.859 us; speedup vs baseline: 1.7716x; 1.0818x over previous
//
#include <hip/hip_runtime.h>
#include <hip/hip_fp16.h>

// ---------------------------------------------------------------------------
// CrowdGNN: 2-layer GCN, N=500k nodes, E=8M edges (+ implicit self loops).
// Round-19 = round-18 champion (195.6us) + partition chunk 8192->16384:
//   sAddr staging eliminated by storing the 10-bit bin id in the payload's
//   spare high bits (wq uses 11/32). Store loop recomputes the global slot
//   address from lbase/lstart (2 LDS reads). LDS = 128KB sPay + 12KB bins
//   -> fits 160KB, 1 block/CU, 16 waves. 489 blocks, bin-runs ~130B.
// Consumers mask wq = (v>>32)&0x7FF (bin bits ride along in the slot).
// Agg unchanged: deg (packed count|wsum u32 LDS atomics, predicated),
// layer1 (u64-packed 2-atomic/edge, BIAS 2^25, rowCnt bias removal),
// layer2 (1 int atomic/edge). wq q11, y fp16, acc q22/q20.
// ---------------------------------------------------------------------------

typedef unsigned long long u64;
typedef long long ll2 __attribute__((ext_vector_type(2)));

#define NPB_SHIFT 9
#define NPB 512
#define MAX_BINS 1024
#define PART_THREADS 1024
#define PART_EPT 16
#define PART_CHUNK (PART_THREADS * PART_EPT)   // 16384 edges per block
#define AGG_THREADS 512

#define Q11      2048.0f
#define INV11    (1.0f / 2048.0f)
#define A1_INV   (1.0f / 4194304.0f)   // q22
#define A2_INV   (1.0f / 1048576.0f)   // q20
#define BIAS     (1u << 25)            // per-edge field bias, > max|c|=2^24.4
#define WQMASK   0x7FFu

struct h4 { __half2 a, b; };

__device__ __forceinline__ float4 h4_to_f4(h4 v) {
    float2 lo = __half22float2(v.a);
    float2 hi = __half22float2(v.b);
    return make_float4(lo.x, lo.y, hi.x, hi.y);
}

// One launch: zero gCnt (all threads) + int64/int32 detect (block 0).
__global__ __launch_bounds__(1024)
void k_prep(const unsigned int* __restrict__ idx_words, int nCheck, int* flag,
            int* __restrict__ gCnt, int B, int nBlocks) {
    int gid = blockIdx.x * 1024 + threadIdx.x;
    for (int i = gid; i < B; i += nBlocks * 1024) gCnt[i] = 0;
    if (blockIdx.x == 0) {
        __shared__ int cnt;
        if (threadIdx.x == 0) cnt = 0;
        __syncthreads();
        int local = 0;
        for (int i = threadIdx.x; i < nCheck; i += 1024)
            local += (idx_words[2 * i + 1] != 0u) ? 1 : 0;
        if (local) atomicAdd(&cnt, local);
        __syncthreads();
        if (threadIdx.x == 0) *flag = (cnt < 8) ? 1 : 0;
    }
}

// Bin-sorted-staging partition; payload = [bin10|wq11]<<32 | [dl9|src23].
// 16384 edges/block; address recomputed at store (no sAddr staging).
__global__ __launch_bounds__(PART_THREADS)
void k_partition(const void* __restrict__ idx, const float* __restrict__ ew,
                 int* __restrict__ gCnt, u64* __restrict__ slots,
                 int E, int B, int cap, const int* __restrict__ flag) {
    __shared__ int lcnt[MAX_BINS];
    __shared__ int lbase[MAX_BINS];
    __shared__ int lstart[MAX_BINS];
    __shared__ u64 sPay[PART_CHUNK];
    __shared__ int waveSum[PART_THREADS / 64];

    const bool is64 = (*flag != 0);
    const int tid = threadIdx.x;
    for (int i = tid; i < MAX_BINS; i += PART_THREADS) lcnt[i] = 0;
    __syncthreads();

    const int base_e = blockIdx.x * PART_CHUNK;
    const int nValid = min(PART_CHUNK, E - base_e);

    u64 pay[PART_EPT];
    int r_[PART_EPT];
#pragma unroll
    for (int i = 0; i < PART_EPT; ++i) {
        int e = base_e + i * PART_THREADS + tid;
        r_[i] = -1;
        if (e < E) {
            int s, d;
            if (is64) {
                const long long* p = (const long long*)idx;
                s = (int)__builtin_nontemporal_load(p + e);
                d = (int)__builtin_nontemporal_load(p + (long long)E + e);
            } else {
                const int* p = (const int*)idx;
                s = __builtin_nontemporal_load(p + e);
                d = __builtin_nontemporal_load(p + E + e);
            }
            float w = __builtin_nontemporal_load(ew + e);
            int bin = d >> NPB_SHIFT;
            unsigned wq = min((unsigned)__float2int_rn(w * Q11), 2047u);
            unsigned hi = ((unsigned)bin << 11) | wq;            // bin10|wq11
            unsigned pk = ((unsigned)(d & (NPB - 1)) << 23) | (unsigned)s;
            pay[i] = ((u64)hi << 32) | pk;
            r_[i] = atomicAdd(&lcnt[bin], 1);
        }
    }
    __syncthreads();

    {
        const int lane = tid & 63, wid = tid >> 6;
        const int v = lcnt[tid];
        int inc = v;
#pragma unroll
        for (int off = 1; off < 64; off <<= 1) {
            int t = __shfl_up(inc, off, 64);
            if (lane >= off) inc += t;
        }
        if (lane == 63) waveSum[wid] = inc;
        __syncthreads();
        if (wid == 0) {
            const int NW = PART_THREADS / 64;
            int wv = (lane < NW) ? waveSum[lane] : 0;
            int winc = wv;
#pragma unroll
            for (int off = 1; off < NW; off <<= 1) {
                int t = __shfl_up(winc, off, 64);
                if (lane >= off) winc += t;
            }
            if (lane < NW) waveSum[lane] = winc - wv;
        }
        __syncthreads();
        lstart[tid] = inc - v + waveSum[wid];
        lbase[tid] = (v > 0 && tid < B) ? atomicAdd(&gCnt[tid], v) : 0;
    }
    __syncthreads();

    // Stage in bin-sorted order (payload only).
#pragma unroll
    for (int i = 0; i < PART_EPT; ++i) {
        if (r_[i] >= 0) {
            int bin = (int)(pay[i] >> 43);
            sPay[lstart[bin] + r_[i]] = pay[i];
        }
    }
    __syncthreads();

    // Coalesced store; address from bin-id in payload + lbase/lstart.
    for (int k = tid; k < nValid; k += PART_THREADS) {
        u64 v = sPay[k];
        int bin = (int)(v >> 43);
        long long pos = (long long)lbase[bin] + (k - lstart[bin]);
        if (pos < cap) slots[(size_t)bin * cap + pos] = v;
    }
}

// 4-wide slot fetch, CACHED loads (nt measured -12us worse on this stream).
__device__ __forceinline__ void load4(const u64* __restrict__ sp, int j, int c,
                                      u64& v0, u64& v1, u64& v2, u64& v3) {
    v0 = v1 = v2 = v3 = 0;
    if (j + 3 < c) {
        ll2 q0 = *((const ll2*)(sp + j));
        ll2 q1 = *((const ll2*)(sp + j) + 1);
        v0 = (u64)q0.x; v1 = (u64)q0.y; v2 = (u64)q1.x; v3 = (u64)q1.y;
    } else if (j < c) {
        v0 = sp[j];
        if (j + 1 < c) v1 = sp[j + 1];
        if (j + 2 < c) v2 = sp[j + 2];
    }
}

// Per-bin: deg/count via packed (1<<20)|wq atomics (PREDICATED — counts must
// be exact for layer1's bias removal); dinv; y = fp16(x*dinv); rowCnt.
__global__ __launch_bounds__(AGG_THREADS, 4)
void k_deg_dinv(const u64* __restrict__ slots, const int* __restrict__ gCnt,
                const float4* __restrict__ x, float* __restrict__ dinv,
                h4* __restrict__ y, int* __restrict__ rowCnt, int N, int cap) {
    __shared__ unsigned degLds[NPB];
    const int b = blockIdx.x;
    for (int t = threadIdx.x; t < NPB; t += AGG_THREADS) degLds[t] = 0u;
    __syncthreads();
    const int c = min(gCnt[b], cap);
    const u64* sp = slots + (size_t)b * cap;
    const int CH = AGG_THREADS * 4;
    for (int base = 0; base < c; base += CH) {
        int j = base + (threadIdx.x << 2);
        u64 v0, v1, v2, v3;
        load4(sp, j, c, v0, v1, v2, v3);
        if (j < c)     atomicAdd(&degLds[((unsigned)v0) >> 23],
                                 (1u << 20) | ((unsigned)(v0 >> 32) & WQMASK));
        if (j + 1 < c) atomicAdd(&degLds[((unsigned)v1) >> 23],
                                 (1u << 20) | ((unsigned)(v1 >> 32) & WQMASK));
        if (j + 2 < c) atomicAdd(&degLds[((unsigned)v2) >> 23],
                                 (1u << 20) | ((unsigned)(v2 >> 32) & WQMASK));
        if (j + 3 < c) atomicAdd(&degLds[((unsigned)v3) >> 23],
                                 (1u << 20) | ((unsigned)(v3 >> 32) & WQMASK));
    }
    __syncthreads();
    for (int t = threadIdx.x; t < NPB; t += AGG_THREADS) {
        int n = (b << NPB_SHIFT) + t;
        if (n < N) {
            unsigned dc = degLds[t];
            float di = rsqrtf(1.0f + (float)(dc & 0xFFFFFu) * INV11);
            dinv[n] = di;
            rowCnt[n] = (int)(dc >> 20);
            float4 xv = x[n];
            h4 hv;
            hv.a = __floats2half2_rn(xv.x * di, xv.y * di);
            hv.b = __floats2half2_rn(xv.z * di, xv.w * di);
            y[n] = hv;
        }
    }
}

// Per-bin layer1: u64-packed LDS atomics (2/edge), biased fields; fused MLP.
__global__ __launch_bounds__(AGG_THREADS, 4)
void k_layer1(const u64* __restrict__ slots, const int* __restrict__ gCnt,
              const float* __restrict__ dinv, const h4* __restrict__ yh,
              const int* __restrict__ rowCnt, const float* __restrict__ W1,
              const float* __restrict__ b1, const float* __restrict__ W2,
              float* __restrict__ z, int N, int cap) {
    __shared__ u64 acc2[NPB][2];    // [n][0]=ch0|ch1, [n][1]=ch2|ch3 (biased)
    __shared__ float dLds[NPB];
    __shared__ float sW1[64], sb1[16], sW2[16];
    if (threadIdx.x < 64) sW1[threadIdx.x] = W1[threadIdx.x];
    if (threadIdx.x < 16) {
        sb1[threadIdx.x] = b1[threadIdx.x];
        sW2[threadIdx.x] = W2[threadIdx.x];
    }
    const int b = blockIdx.x;
    for (int t = threadIdx.x; t < NPB; t += AGG_THREADS) {
        acc2[t][0] = 0ULL; acc2[t][1] = 0ULL;
        int n = (b << NPB_SHIFT) + t;
        dLds[t] = (n < N) ? dinv[n] : 0.0f;
    }
    __syncthreads();
    const int c = min(gCnt[b], cap);
    const u64* sp = slots + (size_t)b * cap;
    const int CH = AGG_THREADS * 4;
    for (int base = 0; base < c; base += CH) {
        int j = base + (threadIdx.x << 2);
        u64 v0, v1, v2, v3;
        load4(sp, j, c, v0, v1, v2, v3);
        unsigned pk0 = (unsigned)v0, pk1 = (unsigned)v1,
                 pk2 = (unsigned)v2, pk3 = (unsigned)v3;
        // wq*y*2048 == (wq/2048)*y*2^22 -> q22 contribution
        float w0 = (float)((unsigned)(v0 >> 32) & WQMASK) * 2048.0f;
        float w1 = (float)((unsigned)(v1 >> 32) & WQMASK) * 2048.0f;
        float w2 = (float)((unsigned)(v2 >> 32) & WQMASK) * 2048.0f;
        float w3 = (float)((unsigned)(v3 >> 32) & WQMASK) * 2048.0f;
        // 4 independent gathers in flight (cached; y table is 4MB)
        h4 g0 = yh[pk0 & 0x7FFFFF];
        h4 g1 = yh[pk1 & 0x7FFFFF];
        h4 g2 = yh[pk2 & 0x7FFFFF];
        h4 g3 = yh[pk3 & 0x7FFFFF];
        float4 f0 = h4_to_f4(g0), f1 = h4_to_f4(g1),
               f2 = h4_to_f4(g2), f3 = h4_to_f4(g3);
        int d0 = pk0 >> 23, d1 = pk1 >> 23, d2 = pk2 >> 23, d3 = pk3 >> 23;
#define PACK2(wf, fa, fb) \
        (((u64)(unsigned)(__float2int_rn((wf) * (fb)) + (int)BIAS) << 32) | \
          (u64)(unsigned)(__float2int_rn((wf) * (fa)) + (int)BIAS))
        if (j < c) {
            atomicAdd(&acc2[d0][0], PACK2(w0, f0.x, f0.y));
            atomicAdd(&acc2[d0][1], PACK2(w0, f0.z, f0.w));
        }
        if (j + 1 < c) {
            atomicAdd(&acc2[d1][0], PACK2(w1, f1.x, f1.y));
            atomicAdd(&acc2[d1][1], PACK2(w1, f1.z, f1.w));
        }
        if (j + 2 < c) {
            atomicAdd(&acc2[d2][0], PACK2(w2, f2.x, f2.y));
            atomicAdd(&acc2[d2][1], PACK2(w2, f2.z, f2.w));
        }
        if (j + 3 < c) {
            atomicAdd(&acc2[d3][0], PACK2(w3, f3.x, f3.y));
            atomicAdd(&acc2[d3][1], PACK2(w3, f3.z, f3.w));
        }
#undef PACK2
    }
    __syncthreads();
    for (int t = threadIdx.x; t < NPB; t += AGG_THREADS) {
        int n = (b << NPB_SHIFT) + t;
        if (n >= N) continue;
        unsigned cb = (unsigned)rowCnt[n] * BIAS;
        u64 p01 = acc2[t][0], p23 = acc2[t][1];
        int a0 = (int)((unsigned)(p01 & 0xFFFFFFFFu) - cb);
        int a1 = (int)((unsigned)(p01 >> 32) - cb);
        int a2 = (int)((unsigned)(p23 & 0xFFFFFFFFu) - cb);
        int a3 = (int)((unsigned)(p23 >> 32) - cb);
        float di = dLds[t];
        float4 yv = h4_to_f4(yh[n]);
        float ax = di * (yv.x + (float)a0 * A1_INV);
        float ay = di * (yv.y + (float)a1 * A1_INV);
        float az = di * (yv.z + (float)a2 * A1_INV);
        float aw = di * (yv.w + (float)a3 * A1_INV);
        float sacc = 0.0f;
#pragma unroll
        for (int k = 0; k < 16; ++k) {
            float h = ax * sW1[k] + ay * sW1[16 + k] + az * sW1[32 + k]
                    + aw * sW1[48 + k] + sb1[k];
            sacc += fmaxf(h, 0.0f) * sW2[k];
        }
        z[n] = sacc * di;
    }
}

// Per-bin layer2: out[n] = di*(z[n] + sum w*z[s]) + b2. 1 atomic/edge;
// sentinel wq=0 contributes 0 -> unconditional adds are safe here.
__global__ __launch_bounds__(AGG_THREADS, 4)
void k_layer2(const u64* __restrict__ slots, const int* __restrict__ gCnt,
              const float* __restrict__ dinv, const float* __restrict__ z,
              const float* __restrict__ b2, float* __restrict__ out,
              int N, int cap) {
    __shared__ int accs[NPB];
    __shared__ float dLds[NPB];
    const int b = blockIdx.x;
    for (int t = threadIdx.x; t < NPB; t += AGG_THREADS) {
        accs[t] = 0;
        int n = (b << NPB_SHIFT) + t;
        dLds[t] = (n < N) ? dinv[n] : 0.0f;
    }
    __syncthreads();
    const int c = min(gCnt[b], cap);
    const u64* sp = slots + (size_t)b * cap;
    const int CH = AGG_THREADS * 4;
    for (int base = 0; base < c; base += CH) {
        int j = base + (threadIdx.x << 2);
        u64 v0, v1, v2, v3;
        load4(sp, j, c, v0, v1, v2, v3);
        unsigned pk0 = (unsigned)v0, pk1 = (unsigned)v1,
                 pk2 = (unsigned)v2, pk3 = (unsigned)v3;
        float z0 = z[pk0 & 0x7FFFFF];
        float z1 = z[pk1 & 0x7FFFFF];
        float z2 = z[pk2 & 0x7FFFFF];
        float z3 = z[pk3 & 0x7FFFFF];
        // w*z*2^20 = wq*z*512
        atomicAdd(&accs[pk0 >> 23],
                  __float2int_rn((float)((unsigned)(v0 >> 32) & WQMASK) * z0 * 512.0f));
        atomicAdd(&accs[pk1 >> 23],
                  __float2int_rn((float)((unsigned)(v1 >> 32) & WQMASK) * z1 * 512.0f));
        atomicAdd(&accs[pk2 >> 23],
                  __float2int_rn((float)((unsigned)(v2 >> 32) & WQMASK) * z2 * 512.0f));
        atomicAdd(&accs[pk3 >> 23],
                  __float2int_rn((float)((unsigned)(v3 >> 32) & WQMASK) * z3 * 512.0f));
    }
    __syncthreads();
    const float bb2 = b2[0];
    for (int t = threadIdx.x; t < NPB; t += AGG_THREADS) {
        int n = (b << NPB_SHIFT) + t;
        if (n < N) out[n] = dLds[t] * (z[n] + (float)accs[t] * A2_INV) + bb2;
    }
}

// ------------------------- fallback (round-1) path -------------------------
__global__ __launch_bounds__(1024)
void k_detect(const unsigned int* __restrict__ idx_words, int nCheck, int* flag) {
    __shared__ int cnt;
    if (threadIdx.x == 0) cnt = 0;
    __syncthreads();
    int local = 0;
    for (int i = threadIdx.x; i < nCheck; i += blockDim.x)
        local += (idx_words[2 * i + 1] != 0u) ? 1 : 0;
    if (local) atomicAdd(&cnt, local);
    __syncthreads();
    if (threadIdx.x == 0) *flag = (cnt < 8) ? 1 : 0;
}

__global__ __launch_bounds__(256)
void k_init(float* __restrict__ deg, int N) {
    int i = blockIdx.x * blockDim.x + threadIdx.x;
    if (i < N) deg[i] = 1.0f;
}

__global__ __launch_bounds__(256)
void k_deg(const void* __restrict__ idx, const float* __restrict__ ew,
           float* __restrict__ deg, int E, const int* __restrict__ flag) {
    const bool is64 = (*flag != 0);
    const int stride = gridDim.x * blockDim.x;
    for (int e = blockIdx.x * blockDim.x + threadIdx.x; e < E; e += stride) {
        int d = is64 ? (int)((const long long*)idx)[(long long)E + e]
                     : ((const int*)idx)[E + e];
        atomicAdd(deg + d, ew[e]);
    }
}

__global__ __launch_bounds__(256)
void k_dinv_accx(float* __restrict__ deg_dinv, const float4* __restrict__ x,
                 float4* __restrict__ accx, int N) {
    int n = blockIdx.x * blockDim.x + threadIdx.x;
    if (n >= N) return;
    float dg = deg_dinv[n];
    float di = (dg > 0.0f) ? rsqrtf(dg) : 0.0f;
    deg_dinv[n] = di;
    float sn = di * di;
    float4 xv = x[n];
    accx[n] = make_float4(xv.x * sn, xv.y * sn, xv.z * sn, xv.w * sn);
}

__global__ __launch_bounds__(256)
void k_scatter1(const void* __restrict__ idx, const float* __restrict__ ew,
                const float* __restrict__ dinv, const float4* __restrict__ x,
                float* __restrict__ accx, int E, const int* __restrict__ flag) {
    const bool is64 = (*flag != 0);
    const int stride = gridDim.x * blockDim.x;
    for (int e = blockIdx.x * blockDim.x + threadIdx.x; e < E; e += stride) {
        int s, d;
        if (is64) {
            const long long* p = (const long long*)idx;
            s = (int)p[e]; d = (int)p[(long long)E + e];
        } else {
            const int* p = (const int*)idx;
            s = p[e]; d = p[E + e];
        }
        float nm = dinv[s] * ew[e] * dinv[d];
        float4 xv = x[s];
        float* dp = accx + (size_t)d * 4;
        atomicAdd(dp + 0, nm * xv.x);
        atomicAdd(dp + 1, nm * xv.y);
        atomicAdd(dp + 2, nm * xv.z);
        atomicAdd(dp + 3, nm * xv.w);
    }
}

__global__ __launch_bounds__(256)
void k_node2(const float4* __restrict__ accx, const float* __restrict__ dinv,
             const float* __restrict__ W1, const float* __restrict__ b1,
             const float* __restrict__ W2, const float* __restrict__ b2,
             float* __restrict__ s2, float* __restrict__ out, int N) {
    __shared__ float sW1[64], sb1[16], sW2[16];
    if (threadIdx.x < 64) sW1[threadIdx.x] = W1[threadIdx.x];
    if (threadIdx.x < 16) {
        sb1[threadIdx.x] = b1[threadIdx.x];
        sW2[threadIdx.x] = W2[threadIdx.x];
    }
    __syncthreads();
    int n = blockIdx.x * blockDim.x + threadIdx.x;
    if (n >= N) return;
    float bb2 = b2[0];
    float4 a = accx[n];
    float acc = 0.0f;
#pragma unroll
    for (int k = 0; k < 16; ++k) {
        float h = a.x * sW1[k] + a.y * sW1[16 + k] + a.z * sW1[32 + k]
                + a.w * sW1[48 + k] + sb1[k];
        acc += fmaxf(h, 0.0f) * sW2[k];
    }
    s2[n] = acc;
    float di = dinv[n];
    out[n] = acc * di * di + bb2;
}

__global__ __launch_bounds__(256)
void k_scatter2(const void* __restrict__ idx, const float* __restrict__ ew,
                const float* __restrict__ dinv, const float* __restrict__ s2,
                float* __restrict__ out, int E, const int* __restrict__ flag) {
    const bool is64 = (*flag != 0);
    const int stride = gridDim.x * blockDim.x;
    for (int e = blockIdx.x * blockDim.x + threadIdx.x; e < E; e += stride) {
        int s, d;
        if (is64) {
            const long long* p = (const long long*)idx;
            s = (int)p[e]; d = (int)p[(long long)E + e];
        } else {
            const int* p = (const int*)idx;
            s = p[e]; d = p[E + e];
        }
        float nm = dinv[s] * ew[e] * dinv[d];
        atomicAdd(out + d, nm * s2[s]);
    }
}

// ---------------------------------------------------------------------------
extern "C" void kernel_launch(void* const* d_in, const int* in_sizes, int n_in,
                              void* d_out, int out_size, void* d_ws, size_t ws_size,
                              hipStream_t stream) {
    const float* x   = (const float*)d_in[0];
    const void*  eix = d_in[1];
    const float* ew  = (const float*)d_in[2];
    const float* W1  = (const float*)d_in[3];
    const float* b1  = (const float*)d_in[4];
    const float* W2  = (const float*)d_in[5];
    const float* b2  = (const float*)d_in[6];
    float* out = (float*)d_out;

    const int N = in_sizes[0] / 4;   // x is [N,4]
    const int E = in_sizes[2];       // edge_weight is [E]

    const int B = (N + NPB - 1) >> NPB_SHIFT;
    int cap = (E / B + 2048 + 3) & ~3;   // mean + ~23 sigma, multiple of 4
    const int nCheck = (E < 65536) ? E : 65536;

    // ws: y h4[N] | slots u64[B*cap] | gCnt[B] | rowCnt[N] | dinv[N] | z[N] | flag
    size_t need = (size_t)N * 8 + (size_t)B * cap * 8
                + (size_t)B * 4 + (size_t)N * 12 + 256;

    bool addr32ok = ((long long)B * cap) < 0xFFFFFFFFLL;

    if (B <= MAX_BINS && N < (1 << 23) && ws_size >= need && addr32ok) {
        h4* y = (h4*)d_ws;
        u64* slots = (u64*)(y + N);
        int*   gCnt = (int*)(slots + (size_t)B * cap);
        int*   rowCnt = gCnt + B;
        float* dinv = (float*)(rowCnt + N);
        float* z    = dinv + N;
        int*   flag = (int*)(z + N);

        const int part_blocks = (E + PART_CHUNK - 1) / PART_CHUNK;

        k_prep<<<2, 1024, 0, stream>>>((const unsigned int*)eix, nCheck, flag,
                                       gCnt, B, 2);
        k_partition<<<part_blocks, PART_THREADS, 0, stream>>>(eix, ew, gCnt, slots,
                                                              E, B, cap, flag);
        k_deg_dinv<<<B, AGG_THREADS, 0, stream>>>(slots, gCnt, (const float4*)x,
                                                  dinv, y, rowCnt, N, cap);
        k_layer1<<<B, AGG_THREADS, 0, stream>>>(slots, gCnt, dinv, y, rowCnt,
                                                W1, b1, W2, z, N, cap);
        k_layer2<<<B, AGG_THREADS, 0, stream>>>(slots, gCnt, dinv, z, b2, out, N, cap);
    } else {
        // fallback: direct atomic scatter (round-1)
        const int nb_n = (N + 255) / 256;
        const int nb_e = min((E + 255) / 256, 16384);
        float* deg  = (float*)d_ws;
        float* accx = deg + N;
        float* s2   = accx + (size_t)4 * N;
        int*   flag = (int*)(s2 + N);

        k_init<<<nb_n, 256, 0, stream>>>(deg, N);
        k_detect<<<1, 1024, 0, stream>>>((const unsigned int*)eix, nCheck, flag);
        k_deg<<<nb_e, 256, 0, stream>>>(eix, ew, deg, E, flag);
        k_dinv_accx<<<nb_n, 256, 0, stream>>>(deg, (const float4*)x, (float4*)accx, N);
        k_scatter1<<<nb_e, 256, 0, stream>>>(eix, ew, deg, (const float4*)x, accx, E, flag);
        k_node2<<<nb_n, 256, 0, stream>>>((const float4*)accx, deg, W1, b1, W2, b2, s2, out, N);
        k_scatter2<<<nb_e, 256, 0, stream>>>(eix, ew, deg, s2, out, E, flag);
    }
}

// Round 20
// 179.193 us; speedup vs baseline: 1.7881x; 1.0093x over previous
//
#include <hip/hip_runtime.h>
#include <hip/hip_fp16.h>

// ---------------------------------------------------------------------------
// CrowdGNN: 2-layer GCN, N=500k nodes, E=8M edges (+ implicit self loops).
// Round-20 = round-19 champion (180.9us) + 8-wide ILP in the two THIN agg
// kernels (deg, layer2): 4x16B slot loads + 8 independent gather/atomic
// chains per thread (they were 2x16B; latency-exposed per the composed
// floor: agg measured 120us vs ~90us stream+atomic model).
//   - k_deg_dinv: 8-wide, PREDICATED adds (exact counts for bias removal),
//     __launch_bounds__(512,8).
//   - k_layer2: 8-wide, unconditional adds (sentinel wq=0 -> +0),
//     __launch_bounds__(512,8).
//   - k_layer1 (u64-packed 2-atomic/edge) and k_partition unchanged.
// Pipeline: prep -> partition (16K-edge blocks, bin-in-payload, LDS
// bin-sorted staging) -> deg/dinv/y -> layer1+MLP -> layer2.
// Fixed-point: wq q11 in slot hi (bin10|wq11); y fp16; acc q22/q20.
// ---------------------------------------------------------------------------

typedef unsigned long long u64;
typedef long long ll2 __attribute__((ext_vector_type(2)));

#define NPB_SHIFT 9
#define NPB 512
#define MAX_BINS 1024
#define PART_THREADS 1024
#define PART_EPT 16
#define PART_CHUNK (PART_THREADS * PART_EPT)   // 16384 edges per block
#define AGG_THREADS 512

#define Q11      2048.0f
#define INV11    (1.0f / 2048.0f)
#define A1_INV   (1.0f / 4194304.0f)   // q22
#define A2_INV   (1.0f / 1048576.0f)   // q20
#define BIAS     (1u << 25)            // per-edge field bias, > max|c|=2^24.4
#define WQMASK   0x7FFu

struct h4 { __half2 a, b; };

__device__ __forceinline__ float4 h4_to_f4(h4 v) {
    float2 lo = __half22float2(v.a);
    float2 hi = __half22float2(v.b);
    return make_float4(lo.x, lo.y, hi.x, hi.y);
}

// One launch: zero gCnt (all threads) + int64/int32 detect (block 0).
__global__ __launch_bounds__(1024)
void k_prep(const unsigned int* __restrict__ idx_words, int nCheck, int* flag,
            int* __restrict__ gCnt, int B, int nBlocks) {
    int gid = blockIdx.x * 1024 + threadIdx.x;
    for (int i = gid; i < B; i += nBlocks * 1024) gCnt[i] = 0;
    if (blockIdx.x == 0) {
        __shared__ int cnt;
        if (threadIdx.x == 0) cnt = 0;
        __syncthreads();
        int local = 0;
        for (int i = threadIdx.x; i < nCheck; i += 1024)
            local += (idx_words[2 * i + 1] != 0u) ? 1 : 0;
        if (local) atomicAdd(&cnt, local);
        __syncthreads();
        if (threadIdx.x == 0) *flag = (cnt < 8) ? 1 : 0;
    }
}

// Bin-sorted-staging partition; payload = [bin10|wq11]<<32 | [dl9|src23].
// 16384 edges/block; address recomputed at store (no sAddr staging).
__global__ __launch_bounds__(PART_THREADS)
void k_partition(const void* __restrict__ idx, const float* __restrict__ ew,
                 int* __restrict__ gCnt, u64* __restrict__ slots,
                 int E, int B, int cap, const int* __restrict__ flag) {
    __shared__ int lcnt[MAX_BINS];
    __shared__ int lbase[MAX_BINS];
    __shared__ int lstart[MAX_BINS];
    __shared__ u64 sPay[PART_CHUNK];
    __shared__ int waveSum[PART_THREADS / 64];

    const bool is64 = (*flag != 0);
    const int tid = threadIdx.x;
    for (int i = tid; i < MAX_BINS; i += PART_THREADS) lcnt[i] = 0;
    __syncthreads();

    const int base_e = blockIdx.x * PART_CHUNK;
    const int nValid = min(PART_CHUNK, E - base_e);

    u64 pay[PART_EPT];
    int r_[PART_EPT];
#pragma unroll
    for (int i = 0; i < PART_EPT; ++i) {
        int e = base_e + i * PART_THREADS + tid;
        r_[i] = -1;
        if (e < E) {
            int s, d;
            if (is64) {
                const long long* p = (const long long*)idx;
                s = (int)__builtin_nontemporal_load(p + e);
                d = (int)__builtin_nontemporal_load(p + (long long)E + e);
            } else {
                const int* p = (const int*)idx;
                s = __builtin_nontemporal_load(p + e);
                d = __builtin_nontemporal_load(p + E + e);
            }
            float w = __builtin_nontemporal_load(ew + e);
            int bin = d >> NPB_SHIFT;
            unsigned wq = min((unsigned)__float2int_rn(w * Q11), 2047u);
            unsigned hi = ((unsigned)bin << 11) | wq;            // bin10|wq11
            unsigned pk = ((unsigned)(d & (NPB - 1)) << 23) | (unsigned)s;
            pay[i] = ((u64)hi << 32) | pk;
            r_[i] = atomicAdd(&lcnt[bin], 1);
        }
    }
    __syncthreads();

    {
        const int lane = tid & 63, wid = tid >> 6;
        const int v = lcnt[tid];
        int inc = v;
#pragma unroll
        for (int off = 1; off < 64; off <<= 1) {
            int t = __shfl_up(inc, off, 64);
            if (lane >= off) inc += t;
        }
        if (lane == 63) waveSum[wid] = inc;
        __syncthreads();
        if (wid == 0) {
            const int NW = PART_THREADS / 64;
            int wv = (lane < NW) ? waveSum[lane] : 0;
            int winc = wv;
#pragma unroll
            for (int off = 1; off < NW; off <<= 1) {
                int t = __shfl_up(winc, off, 64);
                if (lane >= off) winc += t;
            }
            if (lane < NW) waveSum[lane] = winc - wv;
        }
        __syncthreads();
        lstart[tid] = inc - v + waveSum[wid];
        lbase[tid] = (v > 0 && tid < B) ? atomicAdd(&gCnt[tid], v) : 0;
    }
    __syncthreads();

    // Stage in bin-sorted order (payload only).
#pragma unroll
    for (int i = 0; i < PART_EPT; ++i) {
        if (r_[i] >= 0) {
            int bin = (int)(pay[i] >> 43);
            sPay[lstart[bin] + r_[i]] = pay[i];
        }
    }
    __syncthreads();

    // Coalesced store; address from bin-id in payload + lbase/lstart.
    for (int k = tid; k < nValid; k += PART_THREADS) {
        u64 v = sPay[k];
        int bin = (int)(v >> 43);
        long long pos = (long long)lbase[bin] + (k - lstart[bin]);
        if (pos < cap) slots[(size_t)bin * cap + pos] = v;
    }
}

// 4-wide slot fetch, CACHED loads (nt measured -12us worse on this stream).
__device__ __forceinline__ void load4(const u64* __restrict__ sp, int j, int c,
                                      u64& v0, u64& v1, u64& v2, u64& v3) {
    v0 = v1 = v2 = v3 = 0;
    if (j + 3 < c) {
        ll2 q0 = *((const ll2*)(sp + j));
        ll2 q1 = *((const ll2*)(sp + j) + 1);
        v0 = (u64)q0.x; v1 = (u64)q0.y; v2 = (u64)q1.x; v3 = (u64)q1.y;
    } else if (j < c) {
        v0 = sp[j];
        if (j + 1 < c) v1 = sp[j + 1];
        if (j + 2 < c) v2 = sp[j + 2];
    }
}

// 8-wide slot fetch; tail zero-filled (consumers predicate where needed).
__device__ __forceinline__ void load8(const u64* __restrict__ sp, int j, int c,
                                      u64* __restrict__ v) {
    if (j + 7 < c) {
#pragma unroll
        for (int q = 0; q < 4; ++q) {
            ll2 t = *((const ll2*)(sp + j) + q);
            v[2 * q]     = (u64)t.x;
            v[2 * q + 1] = (u64)t.y;
        }
    } else {
#pragma unroll
        for (int q = 0; q < 8; ++q)
            v[q] = (j + q < c) ? sp[j + q] : 0ULL;
    }
}

// Per-bin: deg/count via packed (1<<20)|wq atomics (PREDICATED — counts must
// be exact for layer1's bias removal); dinv; y = fp16(x*dinv); rowCnt.
// 8-wide ILP: 4x16B loads + 8 independent atomic chains per thread.
__global__ __launch_bounds__(AGG_THREADS, 8)
void k_deg_dinv(const u64* __restrict__ slots, const int* __restrict__ gCnt,
                const float4* __restrict__ x, float* __restrict__ dinv,
                h4* __restrict__ y, int* __restrict__ rowCnt, int N, int cap) {
    __shared__ unsigned degLds[NPB];
    const int b = blockIdx.x;
    for (int t = threadIdx.x; t < NPB; t += AGG_THREADS) degLds[t] = 0u;
    __syncthreads();
    const int c = min(gCnt[b], cap);
    const u64* sp = slots + (size_t)b * cap;
    const int CH = AGG_THREADS * 8;
    for (int base = 0; base < c; base += CH) {
        int j = base + (threadIdx.x << 3);
        u64 v[8];
        load8(sp, j, c, v);
#pragma unroll
        for (int q = 0; q < 8; ++q) {
            if (j + q < c)
                atomicAdd(&degLds[((unsigned)v[q]) >> 23],
                          (1u << 20) | ((unsigned)(v[q] >> 32) & WQMASK));
        }
    }
    __syncthreads();
    for (int t = threadIdx.x; t < NPB; t += AGG_THREADS) {
        int n = (b << NPB_SHIFT) + t;
        if (n < N) {
            unsigned dc = degLds[t];
            float di = rsqrtf(1.0f + (float)(dc & 0xFFFFFu) * INV11);
            dinv[n] = di;
            rowCnt[n] = (int)(dc >> 20);
            float4 xv = x[n];
            h4 hv;
            hv.a = __floats2half2_rn(xv.x * di, xv.y * di);
            hv.b = __floats2half2_rn(xv.z * di, xv.w * di);
            y[n] = hv;
        }
    }
}

// Per-bin layer1: u64-packed LDS atomics (2/edge), biased fields; fused MLP.
__global__ __launch_bounds__(AGG_THREADS, 4)
void k_layer1(const u64* __restrict__ slots, const int* __restrict__ gCnt,
              const float* __restrict__ dinv, const h4* __restrict__ yh,
              const int* __restrict__ rowCnt, const float* __restrict__ W1,
              const float* __restrict__ b1, const float* __restrict__ W2,
              float* __restrict__ z, int N, int cap) {
    __shared__ u64 acc2[NPB][2];    // [n][0]=ch0|ch1, [n][1]=ch2|ch3 (biased)
    __shared__ float dLds[NPB];
    __shared__ float sW1[64], sb1[16], sW2[16];
    if (threadIdx.x < 64) sW1[threadIdx.x] = W1[threadIdx.x];
    if (threadIdx.x < 16) {
        sb1[threadIdx.x] = b1[threadIdx.x];
        sW2[threadIdx.x] = W2[threadIdx.x];
    }
    const int b = blockIdx.x;
    for (int t = threadIdx.x; t < NPB; t += AGG_THREADS) {
        acc2[t][0] = 0ULL; acc2[t][1] = 0ULL;
        int n = (b << NPB_SHIFT) + t;
        dLds[t] = (n < N) ? dinv[n] : 0.0f;
    }
    __syncthreads();
    const int c = min(gCnt[b], cap);
    const u64* sp = slots + (size_t)b * cap;
    const int CH = AGG_THREADS * 4;
    for (int base = 0; base < c; base += CH) {
        int j = base + (threadIdx.x << 2);
        u64 v0, v1, v2, v3;
        load4(sp, j, c, v0, v1, v2, v3);
        unsigned pk0 = (unsigned)v0, pk1 = (unsigned)v1,
                 pk2 = (unsigned)v2, pk3 = (unsigned)v3;
        // wq*y*2048 == (wq/2048)*y*2^22 -> q22 contribution
        float w0 = (float)((unsigned)(v0 >> 32) & WQMASK) * 2048.0f;
        float w1 = (float)((unsigned)(v1 >> 32) & WQMASK) * 2048.0f;
        float w2 = (float)((unsigned)(v2 >> 32) & WQMASK) * 2048.0f;
        float w3 = (float)((unsigned)(v3 >> 32) & WQMASK) * 2048.0f;
        // 4 independent gathers in flight (cached; y table is 4MB)
        h4 g0 = yh[pk0 & 0x7FFFFF];
        h4 g1 = yh[pk1 & 0x7FFFFF];
        h4 g2 = yh[pk2 & 0x7FFFFF];
        h4 g3 = yh[pk3 & 0x7FFFFF];
        float4 f0 = h4_to_f4(g0), f1 = h4_to_f4(g1),
               f2 = h4_to_f4(g2), f3 = h4_to_f4(g3);
        int d0 = pk0 >> 23, d1 = pk1 >> 23, d2 = pk2 >> 23, d3 = pk3 >> 23;
#define PACK2(wf, fa, fb) \
        (((u64)(unsigned)(__float2int_rn((wf) * (fb)) + (int)BIAS) << 32) | \
          (u64)(unsigned)(__float2int_rn((wf) * (fa)) + (int)BIAS))
        if (j < c) {
            atomicAdd(&acc2[d0][0], PACK2(w0, f0.x, f0.y));
            atomicAdd(&acc2[d0][1], PACK2(w0, f0.z, f0.w));
        }
        if (j + 1 < c) {
            atomicAdd(&acc2[d1][0], PACK2(w1, f1.x, f1.y));
            atomicAdd(&acc2[d1][1], PACK2(w1, f1.z, f1.w));
        }
        if (j + 2 < c) {
            atomicAdd(&acc2[d2][0], PACK2(w2, f2.x, f2.y));
            atomicAdd(&acc2[d2][1], PACK2(w2, f2.z, f2.w));
        }
        if (j + 3 < c) {
            atomicAdd(&acc2[d3][0], PACK2(w3, f3.x, f3.y));
            atomicAdd(&acc2[d3][1], PACK2(w3, f3.z, f3.w));
        }
#undef PACK2
    }
    __syncthreads();
    for (int t = threadIdx.x; t < NPB; t += AGG_THREADS) {
        int n = (b << NPB_SHIFT) + t;
        if (n >= N) continue;
        unsigned cb = (unsigned)rowCnt[n] * BIAS;
        u64 p01 = acc2[t][0], p23 = acc2[t][1];
        int a0 = (int)((unsigned)(p01 & 0xFFFFFFFFu) - cb);
        int a1 = (int)((unsigned)(p01 >> 32) - cb);
        int a2 = (int)((unsigned)(p23 & 0xFFFFFFFFu) - cb);
        int a3 = (int)((unsigned)(p23 >> 32) - cb);
        float di = dLds[t];
        float4 yv = h4_to_f4(yh[n]);
        float ax = di * (yv.x + (float)a0 * A1_INV);
        float ay = di * (yv.y + (float)a1 * A1_INV);
        float az = di * (yv.z + (float)a2 * A1_INV);
        float aw = di * (yv.w + (float)a3 * A1_INV);
        float sacc = 0.0f;
#pragma unroll
        for (int k = 0; k < 16; ++k) {
            float h = ax * sW1[k] + ay * sW1[16 + k] + az * sW1[32 + k]
                    + aw * sW1[48 + k] + sb1[k];
            sacc += fmaxf(h, 0.0f) * sW2[k];
        }
        z[n] = sacc * di;
    }
}

// Per-bin layer2: out[n] = di*(z[n] + sum w*z[s]) + b2. 1 atomic/edge;
// sentinel wq=0 contributes 0 -> unconditional adds are safe. 8-wide ILP.
__global__ __launch_bounds__(AGG_THREADS, 8)
void k_layer2(const u64* __restrict__ slots, const int* __restrict__ gCnt,
              const float* __restrict__ dinv, const float* __restrict__ z,
              const float* __restrict__ b2, float* __restrict__ out,
              int N, int cap) {
    __shared__ int accs[NPB];
    __shared__ float dLds[NPB];
    const int b = blockIdx.x;
    for (int t = threadIdx.x; t < NPB; t += AGG_THREADS) {
        accs[t] = 0;
        int n = (b << NPB_SHIFT) + t;
        dLds[t] = (n < N) ? dinv[n] : 0.0f;
    }
    __syncthreads();
    const int c = min(gCnt[b], cap);
    const u64* sp = slots + (size_t)b * cap;
    const int CH = AGG_THREADS * 8;
    for (int base = 0; base < c; base += CH) {
        int j = base + (threadIdx.x << 3);
        u64 v[8];
        load8(sp, j, c, v);
        float zf[8];
#pragma unroll
        for (int q = 0; q < 8; ++q)
            zf[q] = z[(unsigned)v[q] & 0x7FFFFF];   // 8 independent gathers
#pragma unroll
        for (int q = 0; q < 8; ++q) {
            // w*z*2^20 = wq*z*512 ; sentinel v=0 -> wq=0 -> adds 0
            atomicAdd(&accs[((unsigned)v[q]) >> 23],
                      __float2int_rn((float)((unsigned)(v[q] >> 32) & WQMASK)
                                     * zf[q] * 512.0f));
        }
    }
    __syncthreads();
    const float bb2 = b2[0];
    for (int t = threadIdx.x; t < NPB; t += AGG_THREADS) {
        int n = (b << NPB_SHIFT) + t;
        if (n < N) out[n] = dLds[t] * (z[n] + (float)accs[t] * A2_INV) + bb2;
    }
}

// ------------------------- fallback (round-1) path -------------------------
__global__ __launch_bounds__(1024)
void k_detect(const unsigned int* __restrict__ idx_words, int nCheck, int* flag) {
    __shared__ int cnt;
    if (threadIdx.x == 0) cnt = 0;
    __syncthreads();
    int local = 0;
    for (int i = threadIdx.x; i < nCheck; i += blockDim.x)
        local += (idx_words[2 * i + 1] != 0u) ? 1 : 0;
    if (local) atomicAdd(&cnt, local);
    __syncthreads();
    if (threadIdx.x == 0) *flag = (cnt < 8) ? 1 : 0;
}

__global__ __launch_bounds__(256)
void k_init(float* __restrict__ deg, int N) {
    int i = blockIdx.x * blockDim.x + threadIdx.x;
    if (i < N) deg[i] = 1.0f;
}

__global__ __launch_bounds__(256)
void k_deg(const void* __restrict__ idx, const float* __restrict__ ew,
           float* __restrict__ deg, int E, const int* __restrict__ flag) {
    const bool is64 = (*flag != 0);
    const int stride = gridDim.x * blockDim.x;
    for (int e = blockIdx.x * blockDim.x + threadIdx.x; e < E; e += stride) {
        int d = is64 ? (int)((const long long*)idx)[(long long)E + e]
                     : ((const int*)idx)[E + e];
        atomicAdd(deg + d, ew[e]);
    }
}

__global__ __launch_bounds__(256)
void k_dinv_accx(float* __restrict__ deg_dinv, const float4* __restrict__ x,
                 float4* __restrict__ accx, int N) {
    int n = blockIdx.x * blockDim.x + threadIdx.x;
    if (n >= N) return;
    float dg = deg_dinv[n];
    float di = (dg > 0.0f) ? rsqrtf(dg) : 0.0f;
    deg_dinv[n] = di;
    float sn = di * di;
    float4 xv = x[n];
    accx[n] = make_float4(xv.x * sn, xv.y * sn, xv.z * sn, xv.w * sn);
}

__global__ __launch_bounds__(256)
void k_scatter1(const void* __restrict__ idx, const float* __restrict__ ew,
                const float* __restrict__ dinv, const float4* __restrict__ x,
                float* __restrict__ accx, int E, const int* __restrict__ flag) {
    const bool is64 = (*flag != 0);
    const int stride = gridDim.x * blockDim.x;
    for (int e = blockIdx.x * blockDim.x + threadIdx.x; e < E; e += stride) {
        int s, d;
        if (is64) {
            const long long* p = (const long long*)idx;
            s = (int)p[e]; d = (int)p[(long long)E + e];
        } else {
            const int* p = (const int*)idx;
            s = p[e]; d = p[E + e];
        }
        float nm = dinv[s] * ew[e] * dinv[d];
        float4 xv = x[s];
        float* dp = accx + (size_t)d * 4;
        atomicAdd(dp + 0, nm * xv.x);
        atomicAdd(dp + 1, nm * xv.y);
        atomicAdd(dp + 2, nm * xv.z);
        atomicAdd(dp + 3, nm * xv.w);
    }
}

__global__ __launch_bounds__(256)
void k_node2(const float4* __restrict__ accx, const float* __restrict__ dinv,
             const float* __restrict__ W1, const float* __restrict__ b1,
             const float* __restrict__ W2, const float* __restrict__ b2,
             float* __restrict__ s2, float* __restrict__ out, int N) {
    __shared__ float sW1[64], sb1[16], sW2[16];
    if (threadIdx.x < 64) sW1[threadIdx.x] = W1[threadIdx.x];
    if (threadIdx.x < 16) {
        sb1[threadIdx.x] = b1[threadIdx.x];
        sW2[threadIdx.x] = W2[threadIdx.x];
    }
    __syncthreads();
    int n = blockIdx.x * blockDim.x + threadIdx.x;
    if (n >= N) return;
    float bb2 = b2[0];
    float4 a = accx[n];
    float acc = 0.0f;
#pragma unroll
    for (int k = 0; k < 16; ++k) {
        float h = a.x * sW1[k] + a.y * sW1[16 + k] + a.z * sW1[32 + k]
                + a.w * sW1[48 + k] + sb1[k];
        acc += fmaxf(h, 0.0f) * sW2[k];
    }
    s2[n] = acc;
    float di = dinv[n];
    out[n] = acc * di * di + bb2;
}

__global__ __launch_bounds__(256)
void k_scatter2(const void* __restrict__ idx, const float* __restrict__ ew,
                const float* __restrict__ dinv, const float* __restrict__ s2,
                float* __restrict__ out, int E, const int* __restrict__ flag) {
    const bool is64 = (*flag != 0);
    const int stride = gridDim.x * blockDim.x;
    for (int e = blockIdx.x * blockDim.x + threadIdx.x; e < E; e += stride) {
        int s, d;
        if (is64) {
            const long long* p = (const long long*)idx;
            s = (int)p[e]; d = (int)p[(long long)E + e];
        } else {
            const int* p = (const int*)idx;
            s = p[e]; d = p[E + e];
        }
        float nm = dinv[s] * ew[e] * dinv[d];
        atomicAdd(out + d, nm * s2[s]);
    }
}

// ---------------------------------------------------------------------------
extern "C" void kernel_launch(void* const* d_in, const int* in_sizes, int n_in,
                              void* d_out, int out_size, void* d_ws, size_t ws_size,
                              hipStream_t stream) {
    const float* x   = (const float*)d_in[0];
    const void*  eix = d_in[1];
    const float* ew  = (const float*)d_in[2];
    const float* W1  = (const float*)d_in[3];
    const float* b1  = (const float*)d_in[4];
    const float* W2  = (const float*)d_in[5];
    const float* b2  = (const float*)d_in[6];
    float* out = (float*)d_out;

    const int N = in_sizes[0] / 4;   // x is [N,4]
    const int E = in_sizes[2];       // edge_weight is [E]

    const int B = (N + NPB - 1) >> NPB_SHIFT;
    int cap = (E / B + 2048 + 7) & ~7;   // mean + ~23 sigma, multiple of 8
    const int nCheck = (E < 65536) ? E : 65536;

    // ws: y h4[N] | slots u64[B*cap] | gCnt[B] | rowCnt[N] | dinv[N] | z[N] | flag
    size_t need = (size_t)N * 8 + (size_t)B * cap * 8
                + (size_t)B * 4 + (size_t)N * 12 + 256;

    bool addr32ok = ((long long)B * cap) < 0xFFFFFFFFLL;

    if (B <= MAX_BINS && N < (1 << 23) && ws_size >= need && addr32ok) {
        h4* y = (h4*)d_ws;
        u64* slots = (u64*)(y + N);
        int*   gCnt = (int*)(slots + (size_t)B * cap);
        int*   rowCnt = gCnt + B;
        float* dinv = (float*)(rowCnt + N);
        float* z    = dinv + N;
        int*   flag = (int*)(z + N);

        const int part_blocks = (E + PART_CHUNK - 1) / PART_CHUNK;

        k_prep<<<2, 1024, 0, stream>>>((const unsigned int*)eix, nCheck, flag,
                                       gCnt, B, 2);
        k_partition<<<part_blocks, PART_THREADS, 0, stream>>>(eix, ew, gCnt, slots,
                                                              E, B, cap, flag);
        k_deg_dinv<<<B, AGG_THREADS, 0, stream>>>(slots, gCnt, (const float4*)x,
                                                  dinv, y, rowCnt, N, cap);
        k_layer1<<<B, AGG_THREADS, 0, stream>>>(slots, gCnt, dinv, y, rowCnt,
                                                W1, b1, W2, z, N, cap);
        k_layer2<<<B, AGG_THREADS, 0, stream>>>(slots, gCnt, dinv, z, b2, out, N, cap);
    } else {
        // fallback: direct atomic scatter (round-1)
        const int nb_n = (N + 255) / 256;
        const int nb_e = min((E + 255) / 256, 16384);
        float* deg  = (float*)d_ws;
        float* accx = deg + N;
        float* s2   = accx + (size_t)4 * N;
        int*   flag = (int*)(s2 + N);

        k_init<<<nb_n, 256, 0, stream>>>(deg, N);
        k_detect<<<1, 1024, 0, stream>>>((const unsigned int*)eix, nCheck, flag);
        k_deg<<<nb_e, 256, 0, stream>>>(eix, ew, deg, E, flag);
        k_dinv_accx<<<nb_n, 256, 0, stream>>>(deg, (const float4*)x, (float4*)accx, N);
        k_scatter1<<<nb_e, 256, 0, stream>>>(eix, ew, deg, (const float4*)x, accx, E, flag);
        k_node2<<<nb_n, 256, 0, stream>>>((const float4*)accx, deg, W1, b1, W2, b2, s2, out, N);
        k_scatter2<<<nb_e, 256, 0, stream>>>(eix, ew, deg, s2, out, E, flag);
    }
}